// Round 7
// baseline (377.697 us; speedup 1.0000x reference)
//
#include <hip/hip_runtime.h>
#include <hip/hip_fp16.h>

typedef _Float16 f16x8 __attribute__((ext_vector_type(8)));
typedef __attribute__((ext_vector_type(4))) float f32x4;

static __device__ __forceinline__ float leaky(float v) { return v >= 0.f ? v : 0.01f * v; }

// ---------------- fused prep: zero ctrs, out-init, weight pack fp16, x->fp16 ----------------
__global__ __launch_bounds__(256) void k_prep_all(
    const float* __restrict__ x, const float* __restrict__ W1, const float* __restrict__ W3,
    const float* __restrict__ fc1w, const float* __restrict__ fc2b,
    int* __restrict__ deg, int* __restrict__ cursor, float* __restrict__ out,
    __half* __restrict__ x16,
    __half* __restrict__ W1T, __half* __restrict__ W3T, __half* __restrict__ F1h,
    int N)
{
    const int gsz = gridDim.x * 256;
    const int gtid = blockIdx.x * 256 + threadIdx.x;
    float ob = fc2b[0];
    for (int i = gtid; i < N; i += gsz) { deg[i] = 0; cursor[i] = 0; out[i] = ob; }
    for (int i = gtid; i < 128 * 512; i += gsz) { int k = i >> 9, n = i & 511; W1T[(n << 7) | k] = __float2half(W1[i]); }
    for (int i = gtid; i < 512 * 128; i += gsz) { int k = i >> 7, n = i & 127; W3T[(n << 9) | k] = __float2half(W3[i]); }
    for (int i = gtid; i < 256 * 128; i += gsz) F1h[i] = __float2half(fc1w[i]);
    for (int i = gtid; i < N * 64; i += gsz) {
        float2 f = ((const float2*)x)[i];
        ((__half2*)x16)[i] = __floats2half2_rn(f.x, f.y);
    }
}

// ---------------- CSR build ----------------
__global__ __launch_bounds__(256) void k_deg(const int* __restrict__ dst, int* __restrict__ deg, int E) {
    int e = blockIdx.x * 256 + threadIdx.x;
    if (e < E) atomicAdd(&deg[dst[e]], 1);
}

__global__ __launch_bounds__(256) void k_scan1(const int* __restrict__ deg, int* __restrict__ part,
                                               int* __restrict__ bsum, int n) {
    __shared__ int s[256];
    int tx = threadIdx.x, i = blockIdx.x * 256 + tx;
    int v = (i < n) ? deg[i] : 0;
    s[tx] = v; __syncthreads();
    for (int off = 1; off < 256; off <<= 1) {
        int t = (tx >= off) ? s[tx - off] : 0;
        __syncthreads();
        s[tx] += t;
        __syncthreads();
    }
    if (i < n) part[i] = s[tx] - v;
    if (tx == 255) bsum[blockIdx.x] = s[255];
}

__global__ __launch_bounds__(256) void k_scan2(int* __restrict__ bsum, int nb) {
    __shared__ int s[256];
    int tx = threadIdx.x;
    int v = (tx < nb) ? bsum[tx] : 0;
    s[tx] = v; __syncthreads();
    for (int off = 1; off < 256; off <<= 1) {
        int t = (tx >= off) ? s[tx - off] : 0;
        __syncthreads();
        s[tx] += t;
        __syncthreads();
    }
    if (tx < nb) bsum[tx] = s[tx] - v;
}

// rowptr + dinv fused
__global__ __launch_bounds__(256) void k_scan3(const int* __restrict__ part, const int* __restrict__ bsum,
                                               const int* __restrict__ deg,
                                               int* __restrict__ rowptr, float* __restrict__ dinv,
                                               int n, int E) {
    int i = blockIdx.x * 256 + threadIdx.x;
    if (i < n) {
        rowptr[i] = part[i] + bsum[i >> 8];
        dinv[i] = rsqrtf((float)deg[i] + 1.0f);
    } else if (i == n) rowptr[n] = E;
}

__global__ __launch_bounds__(256) void k_fill(const int* __restrict__ src, const int* __restrict__ dst,
                                              const int* __restrict__ rowptr, int* __restrict__ cursor,
                                              int* __restrict__ csr, int E) {
    int e = blockIdx.x * 256 + threadIdx.x;
    if (e >= E) return;
    int d = dst[e];
    int pos = atomicAdd(&cursor[d], 1);
    csr[rowptr[d] + pos] = src[e];
}

// ---------------- gather aggregation (fp16 rows in, fp16 out) ----------------
template <bool BIASACT>
__global__ __launch_bounds__(256) void k_gather(const __half* __restrict__ X,
                                                const int* __restrict__ rowptr,
                                                const int* __restrict__ csr,
                                                const float* __restrict__ dinv,
                                                const float* __restrict__ bias,
                                                __half* __restrict__ outp, int N) {
    int wid = __builtin_amdgcn_readfirstlane((int)((blockIdx.x * 256 + threadIdx.x) >> 6));
    if (wid >= N) return;
    int lane = threadIdx.x & 63, c = lane * 2;
    float di = dinv[wid];
    float2 self = __half22float2(*(const __half2*)(X + (size_t)wid * 128 + c));
    float accx = self.x * di, accy = self.y * di;
    int k = rowptr[wid], end = rowptr[wid + 1];
    for (; k < end; k += 8) {
        int ss[8]; float ww[8];
        #pragma unroll
        for (int i = 0; i < 8; ++i) {
            int idx = k + i;
            bool v = idx < end;
            ss[i] = v ? csr[idx] : 0;
            ww[i] = v ? dinv[ss[i]] : 0.f;
        }
        #pragma unroll
        for (int i = 0; i < 8; ++i) {
            float2 f = __half22float2(*(const __half2*)(X + (size_t)ss[i] * 128 + c));
            accx += f.x * ww[i];
            accy += f.y * ww[i];
        }
    }
    accx *= di;
    accy *= di;
    if (BIASACT) {
        accx = leaky(accx + bias[c]);
        accy = leaky(accy + bias[c + 1]);
    }
    *(__half2*)(outp + (size_t)wid * 128 + c) = __floats2half2_rn(accx, accy);
}

// ---------------- MFMA GEMM (single-pass fp16, fp32 accum) ----------------
// A: [M][K] fp16; B: [Ntot][K] fp16. 128x128 tile, K-step 32.
// MODE 0: C = A@B -> fp16 [M][Ntot]
// MODE 1: C = leaky(A@B + bias) -> fp16 [M][Ntot]
// MODE 2: atomicAdd(out[row], sum_col leaky(A@B + bias)[col] * w2[col])
template <int MODE>
__global__ __launch_bounds__(256, 2) void k_mgemm(const __half* __restrict__ Ah,
                                                  const __half* __restrict__ Bh,
                                                  const float* __restrict__ bias,
                                                  const float* __restrict__ w2,
                                                  void* __restrict__ Cout,
                                                  int M, int Ntot, int K) {
    __shared__ __align__(16) _Float16 As[128 * 32];
    __shared__ __align__(16) _Float16 Bs[128 * 32];

    const int tid = threadIdx.x, lane = tid & 63, wid = tid >> 6;
    const int wr = wid >> 1, wc = wid & 1;
    const int nbx = Ntot >> 7;
    const int bx = blockIdx.x % nbx, by = blockIdx.x / nbx;
    const int m0 = by * 128, n0 = bx * 128;

    f32x4 acc[4][4] = {};
    uint4 rA[2], rB[2];

    // staging: thread -> (row = tid>>1, chunk pair), chunk = 8 halfs (16B)
    const int srow = tid >> 1, shf = tid & 1;
    const int ssw = (srow >> 1) & 3;             // XOR swizzle selector
    const __half* Arow;
    {
        int ga = m0 + srow; if (ga >= M) ga = M - 1;
        Arow = Ah + (size_t)ga * K;
    }
    const __half* Brow = Bh + (size_t)(n0 + srow) * K;

    auto issue = [&](int k0) {
        #pragma unroll
        for (int j = 0; j < 2; ++j) {
            int q = shf * 2 + j;
            rA[j] = *(const uint4*)(Arow + k0 + q * 8);
            rB[j] = *(const uint4*)(Brow + k0 + q * 8);
        }
    };
    auto commit = [&]() {
        #pragma unroll
        for (int j = 0; j < 2; ++j) {
            int q = shf * 2 + j;
            int c = q ^ ssw;                     // swizzled LDS chunk
            *(uint4*)(As + srow * 32 + c * 8) = rA[j];
            *(uint4*)(Bs + srow * 32 + c * 8) = rB[j];
        }
    };
    // fragment read: row = rbase + (lane&15), logical chunk q = lane>>4, swizzled
    const int csel = ((lane >> 4) ^ ((lane >> 1) & 3)) * 8;
    auto rdA = [&](int rbase) -> f16x8 {
        int row = rbase + (lane & 15);
        return *(const f16x8*)(As + row * 32 + csel);
    };
    auto rdB = [&](int rbase) -> f16x8 {
        int row = rbase + (lane & 15);
        return *(const f16x8*)(Bs + row * 32 + csel);
    };

    const int nsteps = K >> 5;
    issue(0); commit(); __syncthreads();
    for (int t = 0; t < nsteps; ++t) {
        if (t + 1 < nsteps) issue((t + 1) << 5);
        f16x8 af[4], bf[4];
        #pragma unroll
        for (int i = 0; i < 4; ++i) {
            af[i] = rdA(wr * 64 + i * 16);
            bf[i] = rdB(wc * 64 + i * 16);
        }
        #pragma unroll
        for (int i = 0; i < 4; ++i) {
            #pragma unroll
            for (int n = 0; n < 4; ++n) {
                acc[i][n] = __builtin_amdgcn_mfma_f32_16x16x32_f16(af[i], bf[n], acc[i][n], 0, 0, 0);
            }
        }
        __syncthreads();
        if (t + 1 < nsteps) { commit(); __syncthreads(); }
    }

    if (MODE == 0 || MODE == 1) {
        __half* C = (__half*)Cout;
        #pragma unroll
        for (int i = 0; i < 4; ++i) {
            #pragma unroll
            for (int j = 0; j < 4; ++j) {
                int row = m0 + wr * 64 + i * 16 + (lane >> 4) * 4 + j;
                if (row < M) {
                    #pragma unroll
                    for (int n = 0; n < 4; ++n) {
                        int col = n0 + wc * 64 + n * 16 + (lane & 15);
                        float v = acc[i][n][j];
                        if (MODE == 1) v = leaky(v + bias[col]);
                        C[(size_t)row * Ntot + col] = __float2half(v);
                    }
                }
            }
        }
    } else {
        float* C = (float*)Cout;
        #pragma unroll
        for (int i = 0; i < 4; ++i) {
            #pragma unroll
            for (int j = 0; j < 4; ++j) {
                int row = m0 + wr * 64 + i * 16 + (lane >> 4) * 4 + j;
                float s = 0.f;
                #pragma unroll
                for (int n = 0; n < 4; ++n) {
                    int col = n0 + wc * 64 + n * 16 + (lane & 15);
                    float v = leaky(acc[i][n][j] + bias[col]);
                    s += v * w2[col];
                }
                s += __shfl_xor(s, 8);
                s += __shfl_xor(s, 4);
                s += __shfl_xor(s, 2);
                s += __shfl_xor(s, 1);
                if ((lane & 15) == 0 && row < M) atomicAdd(&C[row], s);
            }
        }
    }
}

extern "C" void kernel_launch(void* const* d_in, const int* in_sizes, int n_in,
                              void* d_out, int out_size, void* d_ws, size_t ws_size,
                              hipStream_t stream) {
    const float* x    = (const float*)d_in[0];
    const int*   ei   = (const int*)d_in[1];
    const float* W1   = (const float*)d_in[2];
    const float* b1   = (const float*)d_in[3];
    const float* W3   = (const float*)d_in[4];
    const float* b3   = (const float*)d_in[5];
    const float* fc1w = (const float*)d_in[6];
    const float* fc1b = (const float*)d_in[7];
    const float* fc2w = (const float*)d_in[8];
    const float* fc2b = (const float*)d_in[9];
    float* out = (float*)d_out;

    int N = in_sizes[0] / 128;   // 50000
    int E = in_sizes[1] / 2;     // 800000
    const int* src = ei;
    const int* dst = ei + E;

    char* ws = (char*)d_ws;
    size_t off = 0;
    auto alloc = [&](size_t bytes) { void* p = ws + off; off += (bytes + 255) & ~255ull; return p; };
    int*   deg    = (int*)alloc((size_t)N * 4);
    int*   cursor = (int*)alloc((size_t)N * 4);
    int*   part   = (int*)alloc((size_t)N * 4);
    int*   bsum   = (int*)alloc(256 * 4);
    int*   rowptr = (int*)alloc((size_t)(N + 1) * 4);
    int*   csr    = (int*)alloc((size_t)E * 4);
    float* dinv   = (float*)alloc((size_t)N * 4);
    __half* x16   = (__half*)alloc((size_t)N * 128 * 2);
    __half* A1h   = (__half*)alloc((size_t)N * 128 * 2);
    __half* H1h   = (__half*)alloc((size_t)N * 512 * 2);
    __half* t2    = (__half*)alloc((size_t)N * 128 * 2);
    __half* A3h   = (__half*)alloc((size_t)N * 128 * 2);
    __half* W1T   = (__half*)alloc((size_t)512 * 128 * 2);
    __half* W3T   = (__half*)alloc((size_t)128 * 512 * 2);
    __half* F1h   = (__half*)alloc((size_t)256 * 128 * 2);
    (void)ws_size; (void)n_in; (void)out_size;

    const int MB128 = (N + 127) / 128;  // 391
    const int nb = (N + 255) / 256;
    dim3 blk(256);

    // 1) fused prep
    k_prep_all<<<1024, blk, 0, stream>>>(x, W1, W3, fc1w, fc2b, deg, cursor, out, x16, W1T, W3T, F1h, N);

    // 2) CSR build
    k_deg<<<(E + 255) / 256, blk, 0, stream>>>(dst, deg, E);
    k_scan1<<<nb, blk, 0, stream>>>(deg, part, bsum, N);
    k_scan2<<<1, blk, 0, stream>>>(bsum, nb);
    k_scan3<<<(N + 256) / 256, blk, 0, stream>>>(part, bsum, deg, rowptr, dinv, N, E);
    k_fill<<<(E + 255) / 256, blk, 0, stream>>>(src, dst, rowptr, cursor, csr, E);

    // 3) agg1 = Agg(x16) -> fp16 [N,128]
    k_gather<false><<<(N * 64 + 255) / 256, blk, 0, stream>>>(x16, rowptr, csr, dinv, nullptr, A1h, N);

    // 4) h1 = leaky(agg1 @ W1 + b1) -> fp16 [N,512]
    k_mgemm<1><<<MB128 * 4, blk, 0, stream>>>(A1h, W1T, b1, nullptr, H1h, N, 512, 128);

    // 5) t2 = h1 @ W3 -> fp16 [N,128]
    k_mgemm<0><<<MB128 * 1, blk, 0, stream>>>(H1h, W3T, nullptr, nullptr, t2, N, 128, 512);

    // 6) h2 = leaky(Agg(t2) + b3) -> fp16 [N,128]
    k_gather<true><<<(N * 64 + 255) / 256, blk, 0, stream>>>(t2, rowptr, csr, dinv, b3, A3h, N);

    // 7) out = leaky(h2 @ fc1_w^T + fc1_b) @ fc2_w^T + fc2_b  (fc2 fused, atomic partials)
    k_mgemm<2><<<MB128 * 2, blk, 0, stream>>>(A3h, F1h, fc1b, fc2w, out, N, 256, 128);
}

// Round 8
// 347.043 us; speedup vs baseline: 1.0883x; 1.0883x over previous
//
#include <hip/hip_runtime.h>
#include <hip/hip_fp16.h>

typedef _Float16 f16x8 __attribute__((ext_vector_type(8)));
typedef __attribute__((ext_vector_type(4))) float f32x4;

static __device__ __forceinline__ float leaky(float v) { return v >= 0.f ? v : 0.01f * v; }

// ---------------- fused prep: weight pack fp16, x->fp16, out init, bucket count ----------------
__global__ __launch_bounds__(256) void k_prep_all(
    const float* __restrict__ x, const float* __restrict__ W1, const float* __restrict__ W3,
    const float* __restrict__ fc1w, const float* __restrict__ fc2b,
    const int* __restrict__ dst, int* __restrict__ bucket_cnt,
    float* __restrict__ out, __half* __restrict__ x16,
    __half* __restrict__ W1T, __half* __restrict__ W3T, __half* __restrict__ F1h,
    int N, int E)
{
    __shared__ int bcnt[256];
    bcnt[threadIdx.x] = 0;
    __syncthreads();
    const int gsz = gridDim.x * 256;
    const int gtid = blockIdx.x * 256 + threadIdx.x;
    float ob = fc2b[0];
    for (int i = gtid; i < N; i += gsz) out[i] = ob;
    for (int i = gtid; i < 128 * 512; i += gsz) { int k = i >> 9, n = i & 511; W1T[(n << 7) | k] = __float2half(W1[i]); }
    for (int i = gtid; i < 512 * 128; i += gsz) { int k = i >> 7, n = i & 127; W3T[(n << 9) | k] = __float2half(W3[i]); }
    for (int i = gtid; i < 256 * 128; i += gsz) F1h[i] = __float2half(fc1w[i]);
    for (int i = gtid; i < N * 64; i += gsz) {
        float2 f = ((const float2*)x)[i];
        ((__half2*)x16)[i] = __floats2half2_rn(f.x, f.y);
    }
    for (int e = gtid; e < E; e += gsz) atomicAdd(&bcnt[dst[e] >> 8], 1);
    __syncthreads();
    int c = bcnt[threadIdx.x];
    if (c > 0) atomicAdd(&bucket_cnt[threadIdx.x], c);
}

// ---------------- bucket prefix (1 block) ----------------
__global__ __launch_bounds__(256) void k_bscan(const int* __restrict__ bucket_cnt,
                                               int* __restrict__ bucket_base,
                                               int* __restrict__ bucket_cursor,
                                               int* __restrict__ rowptr, int N, int E) {
    __shared__ int s[256];
    int tx = threadIdx.x;
    int v = bucket_cnt[tx];
    s[tx] = v; __syncthreads();
    for (int off = 1; off < 256; off <<= 1) {
        int t = (tx >= off) ? s[tx - off] : 0;
        __syncthreads();
        s[tx] += t;
        __syncthreads();
    }
    int excl = s[tx] - v;
    bucket_base[tx] = excl;
    bucket_cursor[tx] = excl;
    if (tx == 0) { bucket_base[256] = E; rowptr[N] = E; }
}

// ---------------- binning fill: pairs (dlocal<<24 | src) grouped by bucket ----------------
__global__ __launch_bounds__(256) void k_bfill(const int* __restrict__ src, const int* __restrict__ dst,
                                               int* __restrict__ bucket_cursor,
                                               unsigned int* __restrict__ pairs, int E) {
    __shared__ int cnt[256];
    __shared__ int base[256];
    const int CH = 4096;
    int c0 = blockIdx.x * CH;
    int cend = c0 + CH < E ? c0 + CH : E;
    int tx = threadIdx.x;
    cnt[tx] = 0;
    __syncthreads();
    for (int i = c0 + tx; i < cend; i += 256) atomicAdd(&cnt[dst[i] >> 8], 1);
    __syncthreads();
    int myc = cnt[tx];
    int mybase = 0;
    if (myc > 0) mybase = atomicAdd(&bucket_cursor[tx], myc);
    __syncthreads();
    cnt[tx] = 0;
    base[tx] = mybase;
    __syncthreads();
    for (int i = c0 + tx; i < cend; i += 256) {
        int d = dst[i];
        int b = d >> 8;
        int pos = base[b] + atomicAdd(&cnt[b], 1);
        pairs[pos] = ((unsigned)(d & 255) << 24) | (unsigned)src[i];
    }
}

// ---------------- per-quarter-bucket: local sort -> coalesced csr/rowptr/dinv ----------------
__global__ __launch_bounds__(256) void k_bsort(const unsigned int* __restrict__ pairs,
                                               const int* __restrict__ bucket_base,
                                               int* __restrict__ rowptr, float* __restrict__ dinv,
                                               int* __restrict__ csr, int N) {
    __shared__ int cnt[256], pre[256], cur[64];
    __shared__ int stage[3072];
    const int B = blockIdx.x >> 2, q = blockIdx.x & 3;
    const int tx = threadIdx.x;
    const int pbase = bucket_base[B], pcnt = bucket_base[B + 1] - pbase;
    cnt[tx] = 0;
    __syncthreads();
    for (int i = tx; i < pcnt; i += 256) atomicAdd(&cnt[pairs[pbase + i] >> 24], 1);
    __syncthreads();
    int v = cnt[tx];
    pre[tx] = v; __syncthreads();
    for (int off = 1; off < 256; off <<= 1) {
        int t = (tx >= off) ? pre[tx - off] : 0;
        __syncthreads();
        pre[tx] += t;
        __syncthreads();
    }
    int node = B * 256 + tx;
    if (node < N) {
        rowptr[node] = pbase + (pre[tx] - v);
        dinv[node] = rsqrtf((float)v + 1.0f);
    }
    const int d0 = q * 64;
    const int qstart = pre[d0] - cnt[d0];
    const int qcnt = pre[d0 + 63] - qstart;
    if (tx < 64) cur[tx] = (pre[d0 + tx] - cnt[d0 + tx]) - qstart;
    __syncthreads();
    if (qcnt == 0) return;
    if (qcnt <= 3072) {
        for (int i = tx; i < pcnt; i += 256) {
            unsigned p = pairs[pbase + i];
            int dl = (int)(p >> 24) - d0;
            if ((unsigned)dl < 64u) {
                int pos = atomicAdd(&cur[dl], 1);
                stage[pos] = (int)(p & 0xFFFFFFu);
            }
        }
        __syncthreads();
        for (int i = tx; i < qcnt; i += 256) csr[pbase + qstart + i] = stage[i];
    } else {
        for (int i = tx; i < pcnt; i += 256) {
            unsigned p = pairs[pbase + i];
            int dl = (int)(p >> 24) - d0;
            if ((unsigned)dl < 64u) {
                int pos = atomicAdd(&cur[dl], 1);
                csr[pbase + qstart + pos] = (int)(p & 0xFFFFFFu);
            }
        }
    }
}

// ---------------- gather aggregation (fp16 rows in, fp16 out) ----------------
template <bool BIASACT>
__global__ __launch_bounds__(256) void k_gather(const __half* __restrict__ X,
                                                const int* __restrict__ rowptr,
                                                const int* __restrict__ csr,
                                                const float* __restrict__ dinv,
                                                const float* __restrict__ bias,
                                                __half* __restrict__ outp, int N) {
    int wid = __builtin_amdgcn_readfirstlane((int)((blockIdx.x * 256 + threadIdx.x) >> 6));
    if (wid >= N) return;
    int lane = threadIdx.x & 63, c = lane * 2;
    float di = dinv[wid];
    float2 self = __half22float2(*(const __half2*)(X + (size_t)wid * 128 + c));
    float accx = self.x * di, accy = self.y * di;
    int k = rowptr[wid], end = rowptr[wid + 1];
    for (; k < end; k += 8) {
        int ss[8]; float ww[8];
        #pragma unroll
        for (int i = 0; i < 8; ++i) {
            int idx = k + i;
            bool v = idx < end;
            ss[i] = v ? csr[idx] : 0;
            ww[i] = v ? dinv[ss[i]] : 0.f;
        }
        #pragma unroll
        for (int i = 0; i < 8; ++i) {
            float2 f = __half22float2(*(const __half2*)(X + (size_t)ss[i] * 128 + c));
            accx += f.x * ww[i];
            accy += f.y * ww[i];
        }
    }
    accx *= di;
    accy *= di;
    if (BIASACT) {
        accx = leaky(accx + bias[c]);
        accy = leaky(accy + bias[c + 1]);
    }
    *(__half2*)(outp + (size_t)wid * 128 + c) = __floats2half2_rn(accx, accy);
}

// ---------------- MFMA GEMM (single-pass fp16, fp32 accum) ----------------
// A: [M][K] fp16; B: [Ntot][K] fp16. 128x128 tile, K-step 32.
// MODE 0: C = A@B -> fp16; MODE 1: C = leaky(A@B+bias) -> fp16;
// MODE 2: atomicAdd(out[row], sum_col leaky(A@B+bias)[col]*w2[col])
template <int MODE>
__global__ __launch_bounds__(256, 2) void k_mgemm(const __half* __restrict__ Ah,
                                                  const __half* __restrict__ Bh,
                                                  const float* __restrict__ bias,
                                                  const float* __restrict__ w2,
                                                  void* __restrict__ Cout,
                                                  int M, int Ntot, int K) {
    __shared__ __align__(16) _Float16 As[128 * 32];
    __shared__ __align__(16) _Float16 Bs[128 * 32];

    const int tid = threadIdx.x, lane = tid & 63, wid = tid >> 6;
    const int wr = wid >> 1, wc = wid & 1;
    const int nbx = Ntot >> 7;
    const int bx = blockIdx.x % nbx, by = blockIdx.x / nbx;
    const int m0 = by * 128, n0 = bx * 128;

    f32x4 acc[4][4] = {};
    uint4 rA[2], rB[2];

    const int srow = tid >> 1, shf = tid & 1;
    const int ssw = (srow >> 1) & 3;
    const __half* Arow;
    {
        int ga = m0 + srow; if (ga >= M) ga = M - 1;
        Arow = Ah + (size_t)ga * K;
    }
    const __half* Brow = Bh + (size_t)(n0 + srow) * K;

    auto issue = [&](int k0) {
        #pragma unroll
        for (int j = 0; j < 2; ++j) {
            int qq = shf * 2 + j;
            rA[j] = *(const uint4*)(Arow + k0 + qq * 8);
            rB[j] = *(const uint4*)(Brow + k0 + qq * 8);
        }
    };
    auto commit = [&]() {
        #pragma unroll
        for (int j = 0; j < 2; ++j) {
            int qq = shf * 2 + j;
            int c = qq ^ ssw;
            *(uint4*)(As + srow * 32 + c * 8) = rA[j];
            *(uint4*)(Bs + srow * 32 + c * 8) = rB[j];
        }
    };
    const int csel = ((lane >> 4) ^ ((lane >> 1) & 3)) * 8;
    auto rdA = [&](int rbase) -> f16x8 {
        int row = rbase + (lane & 15);
        return *(const f16x8*)(As + row * 32 + csel);
    };
    auto rdB = [&](int rbase) -> f16x8 {
        int row = rbase + (lane & 15);
        return *(const f16x8*)(Bs + row * 32 + csel);
    };

    const int nsteps = K >> 5;
    issue(0); commit(); __syncthreads();
    for (int t = 0; t < nsteps; ++t) {
        if (t + 1 < nsteps) issue((t + 1) << 5);
        f16x8 af[4], bf[4];
        #pragma unroll
        for (int i = 0; i < 4; ++i) {
            af[i] = rdA(wr * 64 + i * 16);
            bf[i] = rdB(wc * 64 + i * 16);
        }
        #pragma unroll
        for (int i = 0; i < 4; ++i) {
            #pragma unroll
            for (int n = 0; n < 4; ++n) {
                acc[i][n] = __builtin_amdgcn_mfma_f32_16x16x32_f16(af[i], bf[n], acc[i][n], 0, 0, 0);
            }
        }
        __syncthreads();
        if (t + 1 < nsteps) { commit(); __syncthreads(); }
    }

    if (MODE == 0 || MODE == 1) {
        __half* C = (__half*)Cout;
        #pragma unroll
        for (int i = 0; i < 4; ++i) {
            #pragma unroll
            for (int j = 0; j < 4; ++j) {
                int row = m0 + wr * 64 + i * 16 + (lane >> 4) * 4 + j;
                if (row < M) {
                    #pragma unroll
                    for (int n = 0; n < 4; ++n) {
                        int col = n0 + wc * 64 + n * 16 + (lane & 15);
                        float v = acc[i][n][j];
                        if (MODE == 1) v = leaky(v + bias[col]);
                        C[(size_t)row * Ntot + col] = __float2half(v);
                    }
                }
            }
        }
    } else {
        float* C = (float*)Cout;
        #pragma unroll
        for (int i = 0; i < 4; ++i) {
            #pragma unroll
            for (int j = 0; j < 4; ++j) {
                int row = m0 + wr * 64 + i * 16 + (lane >> 4) * 4 + j;
                float s = 0.f;
                #pragma unroll
                for (int n = 0; n < 4; ++n) {
                    int col = n0 + wc * 64 + n * 16 + (lane & 15);
                    float v = leaky(acc[i][n][j] + bias[col]);
                    s += v * w2[col];
                }
                s += __shfl_xor(s, 8);
                s += __shfl_xor(s, 4);
                s += __shfl_xor(s, 2);
                s += __shfl_xor(s, 1);
                if ((lane & 15) == 0 && row < M) atomicAdd(&C[row], s);
            }
        }
    }
}

extern "C" void kernel_launch(void* const* d_in, const int* in_sizes, int n_in,
                              void* d_out, int out_size, void* d_ws, size_t ws_size,
                              hipStream_t stream) {
    const float* x    = (const float*)d_in[0];
    const int*   ei   = (const int*)d_in[1];
    const float* W1   = (const float*)d_in[2];
    const float* b1   = (const float*)d_in[3];
    const float* W3   = (const float*)d_in[4];
    const float* b3   = (const float*)d_in[5];
    const float* fc1w = (const float*)d_in[6];
    const float* fc1b = (const float*)d_in[7];
    const float* fc2w = (const float*)d_in[8];
    const float* fc2b = (const float*)d_in[9];
    float* out = (float*)d_out;

    int N = in_sizes[0] / 128;   // 50000
    int E = in_sizes[1] / 2;     // 800000
    const int* src = ei;
    const int* dst = ei + E;

    char* ws = (char*)d_ws;
    size_t off = 0;
    auto alloc = [&](size_t bytes) { void* p = ws + off; off += (bytes + 255) & ~255ull; return p; };
    int*   bucket_cnt    = (int*)alloc(257 * 4);
    int*   bucket_base   = (int*)alloc(257 * 4);
    int*   bucket_cursor = (int*)alloc(257 * 4);
    int*   rowptr = (int*)alloc((size_t)(N + 1) * 4);
    unsigned int* pairs = (unsigned int*)alloc((size_t)E * 4);
    int*   csr    = (int*)alloc((size_t)E * 4);
    float* dinv   = (float*)alloc((size_t)N * 4);
    __half* x16   = (__half*)alloc((size_t)N * 128 * 2);
    __half* A1h   = (__half*)alloc((size_t)N * 128 * 2);
    __half* H1h   = (__half*)alloc((size_t)N * 512 * 2);
    __half* t2    = (__half*)alloc((size_t)N * 128 * 2);
    __half* A3h   = (__half*)alloc((size_t)N * 128 * 2);
    __half* W1T   = (__half*)alloc((size_t)512 * 128 * 2);
    __half* W3T   = (__half*)alloc((size_t)128 * 512 * 2);
    __half* F1h   = (__half*)alloc((size_t)256 * 128 * 2);
    (void)ws_size; (void)n_in; (void)out_size;

    const int MB128 = (N + 127) / 128;  // 391
    const int NB = (N + 255) >> 8;      // 196
    dim3 blk(256);

    // 0) zero bucket counters
    hipMemsetAsync(bucket_cnt, 0, 257 * 4, stream);

    // 1) fused prep + bucket count
    k_prep_all<<<1024, blk, 0, stream>>>(x, W1, W3, fc1w, fc2b, dst, bucket_cnt,
                                         out, x16, W1T, W3T, F1h, N, E);

    // 2) bucket prefix
    k_bscan<<<1, blk, 0, stream>>>(bucket_cnt, bucket_base, bucket_cursor, rowptr, N, E);

    // 3) binning fill -> pairs
    k_bfill<<<(E + 4095) / 4096, blk, 0, stream>>>(src, dst, bucket_cursor, pairs, E);

    // 4) per-quarter local sort -> csr, rowptr, dinv (all coalesced)
    k_bsort<<<NB * 4, blk, 0, stream>>>(pairs, bucket_base, rowptr, dinv, csr, N);

    // 5) agg1 = Agg(x16) -> fp16 [N,128]
    k_gather<false><<<(N * 64 + 255) / 256, blk, 0, stream>>>(x16, rowptr, csr, dinv, nullptr, A1h, N);

    // 6) h1 = leaky(agg1 @ W1 + b1) -> fp16 [N,512]
    k_mgemm<1><<<MB128 * 4, blk, 0, stream>>>(A1h, W1T, b1, nullptr, H1h, N, 512, 128);

    // 7) t2 = h1 @ W3 -> fp16 [N,128]
    k_mgemm<0><<<MB128 * 1, blk, 0, stream>>>(H1h, W3T, nullptr, nullptr, t2, N, 128, 512);

    // 8) h2 = leaky(Agg(t2) + b3) -> fp16 [N,128]
    k_gather<true><<<(N * 64 + 255) / 256, blk, 0, stream>>>(t2, rowptr, csr, dinv, b3, A3h, N);

    // 9) out = leaky(h2 @ fc1_w^T + fc1_b) @ fc2_w^T + fc2_b  (fc2 fused, atomic partials)
    k_mgemm<2><<<MB128 * 2, blk, 0, stream>>>(A3h, F1h, fc1b, fc2w, out, N, 256, 128);
}

// Round 9
// 343.837 us; speedup vs baseline: 1.0985x; 1.0093x over previous
//
#include <hip/hip_runtime.h>
#include <hip/hip_fp16.h>

typedef _Float16 f16x8 __attribute__((ext_vector_type(8)));
typedef __attribute__((ext_vector_type(4))) float f32x4;

static __device__ __forceinline__ float leaky(float v) { return v >= 0.f ? v : 0.01f * v; }

// ---------------- fused prep: weight pack fp16, x->fp16, out init, bucket count ----------------
__global__ __launch_bounds__(256) void k_prep_all(
    const float* __restrict__ x, const float* __restrict__ W1, const float* __restrict__ W3,
    const float* __restrict__ fc1w, const float* __restrict__ fc2b,
    const int* __restrict__ dst, int* __restrict__ bucket_cnt,
    float* __restrict__ out, __half* __restrict__ x16,
    __half* __restrict__ W1T, __half* __restrict__ W3T, __half* __restrict__ F1h,
    int N, int E)
{
    __shared__ int bcnt[256];
    bcnt[threadIdx.x] = 0;
    __syncthreads();
    const int gsz = gridDim.x * 256;
    const int gtid = blockIdx.x * 256 + threadIdx.x;
    float ob = fc2b[0];
    for (int i = gtid; i < N; i += gsz) out[i] = ob;
    for (int i = gtid; i < 128 * 512; i += gsz) { int k = i >> 9, n = i & 511; W1T[(n << 7) | k] = __float2half(W1[i]); }
    for (int i = gtid; i < 512 * 128; i += gsz) { int k = i >> 7, n = i & 127; W3T[(n << 9) | k] = __float2half(W3[i]); }
    for (int i = gtid; i < 256 * 128; i += gsz) F1h[i] = __float2half(fc1w[i]);
    for (int i = gtid; i < N * 64; i += gsz) {
        float2 f = ((const float2*)x)[i];
        ((__half2*)x16)[i] = __floats2half2_rn(f.x, f.y);
    }
    for (int e = gtid; e < E; e += gsz) atomicAdd(&bcnt[dst[e] >> 8], 1);
    __syncthreads();
    int c = bcnt[threadIdx.x];
    if (c > 0) atomicAdd(&bucket_cnt[threadIdx.x], c);
}

// ---------------- bucket prefix (1 block) ----------------
__global__ __launch_bounds__(256) void k_bscan(const int* __restrict__ bucket_cnt,
                                               int* __restrict__ bucket_base,
                                               int* __restrict__ bucket_cursor,
                                               int* __restrict__ rowptr, int N, int E) {
    __shared__ int s[256];
    int tx = threadIdx.x;
    int v = bucket_cnt[tx];
    s[tx] = v; __syncthreads();
    for (int off = 1; off < 256; off <<= 1) {
        int t = (tx >= off) ? s[tx - off] : 0;
        __syncthreads();
        s[tx] += t;
        __syncthreads();
    }
    int excl = s[tx] - v;
    bucket_base[tx] = excl;
    bucket_cursor[tx] = excl;
    if (tx == 0) { bucket_base[256] = E; rowptr[N] = E; }
}

// ---------------- binning fill: pairs (dlocal<<24 | src) grouped by bucket ----------------
__global__ __launch_bounds__(256) void k_bfill(const int* __restrict__ src, const int* __restrict__ dst,
                                               int* __restrict__ bucket_cursor,
                                               unsigned int* __restrict__ pairs, int E) {
    __shared__ int cnt[256];
    __shared__ int base[256];
    const int CH = 4096;
    int c0 = blockIdx.x * CH;
    int cend = c0 + CH < E ? c0 + CH : E;
    int tx = threadIdx.x;
    cnt[tx] = 0;
    __syncthreads();
    for (int i = c0 + tx; i < cend; i += 256) atomicAdd(&cnt[dst[i] >> 8], 1);
    __syncthreads();
    int myc = cnt[tx];
    int mybase = 0;
    if (myc > 0) mybase = atomicAdd(&bucket_cursor[tx], myc);
    __syncthreads();
    cnt[tx] = 0;
    base[tx] = mybase;
    __syncthreads();
    for (int i = c0 + tx; i < cend; i += 256) {
        int d = dst[i];
        int b = d >> 8;
        int pos = base[b] + atomicAdd(&cnt[b], 1);
        pairs[pos] = ((unsigned)(d & 255) << 24) | (unsigned)src[i];
    }
}

// ---------------- per-quarter-bucket: local sort -> coalesced csr/rowptr/dinv ----------------
__global__ __launch_bounds__(256) void k_bsort(const unsigned int* __restrict__ pairs,
                                               const int* __restrict__ bucket_base,
                                               int* __restrict__ rowptr, float* __restrict__ dinv,
                                               int* __restrict__ csr, int N) {
    __shared__ int cnt[256], pre[256], cur[64];
    __shared__ int stage[3072];
    const int B = blockIdx.x >> 2, q = blockIdx.x & 3;
    const int tx = threadIdx.x;
    const int pbase = bucket_base[B], pcnt = bucket_base[B + 1] - pbase;
    cnt[tx] = 0;
    __syncthreads();
    for (int i = tx; i < pcnt; i += 256) atomicAdd(&cnt[pairs[pbase + i] >> 24], 1);
    __syncthreads();
    int v = cnt[tx];
    pre[tx] = v; __syncthreads();
    for (int off = 1; off < 256; off <<= 1) {
        int t = (tx >= off) ? pre[tx - off] : 0;
        __syncthreads();
        pre[tx] += t;
        __syncthreads();
    }
    int node = B * 256 + tx;
    if (node < N) {
        rowptr[node] = pbase + (pre[tx] - v);
        dinv[node] = rsqrtf((float)v + 1.0f);
    }
    const int d0 = q * 64;
    const int qstart = pre[d0] - cnt[d0];
    const int qcnt = pre[d0 + 63] - qstart;
    if (tx < 64) cur[tx] = (pre[d0 + tx] - cnt[d0 + tx]) - qstart;
    __syncthreads();
    if (qcnt == 0) return;
    if (qcnt <= 3072) {
        for (int i = tx; i < pcnt; i += 256) {
            unsigned p = pairs[pbase + i];
            int dl = (int)(p >> 24) - d0;
            if ((unsigned)dl < 64u) {
                int pos = atomicAdd(&cur[dl], 1);
                stage[pos] = (int)(p & 0xFFFFFFu);
            }
        }
        __syncthreads();
        for (int i = tx; i < qcnt; i += 256) csr[pbase + qstart + i] = stage[i];
    } else {
        for (int i = tx; i < pcnt; i += 256) {
            unsigned p = pairs[pbase + i];
            int dl = (int)(p >> 24) - d0;
            if ((unsigned)dl < 64u) {
                int pos = atomicAdd(&cur[dl], 1);
                csr[pbase + qstart + pos] = (int)(p & 0xFFFFFFu);
            }
        }
    }
}

// ---------------- gather aggregation (fp16 rows in, fp16 out) ----------------
template <bool BIASACT>
__global__ __launch_bounds__(256) void k_gather(const __half* __restrict__ X,
                                                const int* __restrict__ rowptr,
                                                const int* __restrict__ csr,
                                                const float* __restrict__ dinv,
                                                const float* __restrict__ bias,
                                                __half* __restrict__ outp, int N) {
    int wid = __builtin_amdgcn_readfirstlane((int)((blockIdx.x * 256 + threadIdx.x) >> 6));
    if (wid >= N) return;
    int lane = threadIdx.x & 63, c = lane * 2;
    float di = dinv[wid];
    float2 self = __half22float2(*(const __half2*)(X + (size_t)wid * 128 + c));
    float accx = self.x * di, accy = self.y * di;
    int k = rowptr[wid], end = rowptr[wid + 1];
    for (; k < end; k += 8) {
        int ss[8]; float ww[8];
        #pragma unroll
        for (int i = 0; i < 8; ++i) {
            int idx = k + i;
            bool v = idx < end;
            ss[i] = v ? csr[idx] : 0;
            ww[i] = v ? dinv[ss[i]] : 0.f;
        }
        #pragma unroll
        for (int i = 0; i < 8; ++i) {
            float2 f = __half22float2(*(const __half2*)(X + (size_t)ss[i] * 128 + c));
            accx += f.x * ww[i];
            accy += f.y * ww[i];
        }
    }
    accx *= di;
    accy *= di;
    if (BIASACT) {
        accx = leaky(accx + bias[c]);
        accy = leaky(accy + bias[c + 1]);
    }
    *(__half2*)(outp + (size_t)wid * 128 + c) = __floats2half2_rn(accx, accy);
}

// ---------------- MFMA GEMM (single-pass fp16, fp32 accum) ----------------
// A: [M][K] fp16; B: [Ntot][K] fp16. 128x128 tile, K-step 32.
// MODE 0: C = A@B -> fp16; MODE 1: C = leaky(A@B+bias) -> fp16;
// MODE 2: atomicAdd(out[row], sum_col leaky(A@B+bias)[col]*w2[col])
template <int MODE>
__global__ __launch_bounds__(256, 2) void k_mgemm(const __half* __restrict__ Ah,
                                                  const __half* __restrict__ Bh,
                                                  const float* __restrict__ bias,
                                                  const float* __restrict__ w2,
                                                  void* __restrict__ Cout,
                                                  int M, int Ntot, int K) {
    __shared__ __align__(16) _Float16 smem[128 * 32 * 2];   // As | Bs; reused as Cs in epilogue
    _Float16* As = smem;
    _Float16* Bs = smem + 4096;

    const int tid = threadIdx.x, lane = tid & 63, wid = tid >> 6;
    const int wr = wid >> 1, wc = wid & 1;
    const int nbx = Ntot >> 7;
    const int bx = blockIdx.x % nbx, by = blockIdx.x / nbx;
    const int m0 = by * 128, n0 = bx * 128;

    f32x4 acc[4][4] = {};
    uint4 rA[2], rB[2];

    const int srow = tid >> 1, shf = tid & 1;
    const int ssw = (srow >> 1) & 3;
    const __half* Arow;
    {
        int ga = m0 + srow; if (ga >= M) ga = M - 1;
        Arow = Ah + (size_t)ga * K;
    }
    const __half* Brow = Bh + (size_t)(n0 + srow) * K;

    auto issue = [&](int k0) {
        #pragma unroll
        for (int j = 0; j < 2; ++j) {
            int qq = shf * 2 + j;
            rA[j] = *(const uint4*)(Arow + k0 + qq * 8);
            rB[j] = *(const uint4*)(Brow + k0 + qq * 8);
        }
    };
    auto commit = [&]() {
        #pragma unroll
        for (int j = 0; j < 2; ++j) {
            int qq = shf * 2 + j;
            int c = qq ^ ssw;
            *(uint4*)(As + srow * 32 + c * 8) = rA[j];
            *(uint4*)(Bs + srow * 32 + c * 8) = rB[j];
        }
    };
    const int csel = ((lane >> 4) ^ ((lane >> 1) & 3)) * 8;
    auto rdA = [&](int rbase) -> f16x8 {
        int row = rbase + (lane & 15);
        return *(const f16x8*)(As + row * 32 + csel);
    };
    auto rdB = [&](int rbase) -> f16x8 {
        int row = rbase + (lane & 15);
        return *(const f16x8*)(Bs + row * 32 + csel);
    };

    const int nsteps = K >> 5;
    issue(0); commit(); __syncthreads();
    for (int t = 0; t < nsteps; ++t) {
        if (t + 1 < nsteps) issue((t + 1) << 5);
        f16x8 af[4], bf[4];
        #pragma unroll
        for (int i = 0; i < 4; ++i) {
            af[i] = rdA(wr * 64 + i * 16);
            bf[i] = rdB(wc * 64 + i * 16);
        }
        #pragma unroll
        for (int i = 0; i < 4; ++i) {
            #pragma unroll
            for (int n = 0; n < 4; ++n) {
                acc[i][n] = __builtin_amdgcn_mfma_f32_16x16x32_f16(af[i], bf[n], acc[i][n], 0, 0, 0);
            }
        }
        __syncthreads();
        if (t + 1 < nsteps) { commit(); __syncthreads(); }
    }

    if (MODE == 0 || MODE == 1) {
        // LDS-restaged coalesced epilogue: 4 passes of 32 rows; [32][136] fp16 tile
        __half* C = (__half*)Cout;
        _Float16* Cs = smem;    // 32*136*2B = 8704B, fits in the 16KB
        #pragma unroll
        for (int p = 0; p < 4; ++p) {
            __syncthreads();
            if (wr == (p >> 1)) {
                #pragma unroll
                for (int ii = 0; ii < 2; ++ii) {
                    int i = (p & 1) * 2 + ii;
                    #pragma unroll
                    for (int j = 0; j < 4; ++j) {
                        int lr = ii * 16 + ((lane >> 4) << 2) + j;
                        #pragma unroll
                        for (int n = 0; n < 4; ++n) {
                            int col = wc * 64 + n * 16 + (lane & 15);
                            float v = acc[i][n][j];
                            if (MODE == 1) v = leaky(v + bias[n0 + col]);
                            Cs[lr * 136 + col] = (_Float16)v;
                        }
                    }
                }
            }
            __syncthreads();
            #pragma unroll
            for (int it = 0; it < 2; ++it) {
                int idx = (it * 256 + tid) * 8;
                int row = idx >> 7, col = idx & 127;
                int gr = m0 + p * 32 + row;
                if (gr < M)
                    *(uint4*)(C + (size_t)gr * Ntot + n0 + col) = *(const uint4*)(Cs + row * 136 + col);
            }
        }
    } else {
        float* C = (float*)Cout;
        #pragma unroll
        for (int i = 0; i < 4; ++i) {
            #pragma unroll
            for (int j = 0; j < 4; ++j) {
                int row = m0 + wr * 64 + i * 16 + (lane >> 4) * 4 + j;
                float s = 0.f;
                #pragma unroll
                for (int n = 0; n < 4; ++n) {
                    int col = n0 + wc * 64 + n * 16 + (lane & 15);
                    float v = leaky(acc[i][n][j] + bias[col]);
                    s += v * w2[col];
                }
                s += __shfl_xor(s, 8);
                s += __shfl_xor(s, 4);
                s += __shfl_xor(s, 2);
                s += __shfl_xor(s, 1);
                if ((lane & 15) == 0 && row < M) atomicAdd(&C[row], s);
            }
        }
    }
}

extern "C" void kernel_launch(void* const* d_in, const int* in_sizes, int n_in,
                              void* d_out, int out_size, void* d_ws, size_t ws_size,
                              hipStream_t stream) {
    const float* x    = (const float*)d_in[0];
    const int*   ei   = (const int*)d_in[1];
    const float* W1   = (const float*)d_in[2];
    const float* b1   = (const float*)d_in[3];
    const float* W3   = (const float*)d_in[4];
    const float* b3   = (const float*)d_in[5];
    const float* fc1w = (const float*)d_in[6];
    const float* fc1b = (const float*)d_in[7];
    const float* fc2w = (const float*)d_in[8];
    const float* fc2b = (const float*)d_in[9];
    float* out = (float*)d_out;

    int N = in_sizes[0] / 128;   // 50000
    int E = in_sizes[1] / 2;     // 800000
    const int* src = ei;
    const int* dst = ei + E;

    char* ws = (char*)d_ws;
    size_t off = 0;
    auto alloc = [&](size_t bytes) { void* p = ws + off; off += (bytes + 255) & ~255ull; return p; };
    int*   bucket_cnt    = (int*)alloc(257 * 4);
    int*   bucket_base   = (int*)alloc(257 * 4);
    int*   bucket_cursor = (int*)alloc(257 * 4);
    int*   rowptr = (int*)alloc((size_t)(N + 1) * 4);
    unsigned int* pairs = (unsigned int*)alloc((size_t)E * 4);
    int*   csr    = (int*)alloc((size_t)E * 4);
    float* dinv   = (float*)alloc((size_t)N * 4);
    __half* x16   = (__half*)alloc((size_t)N * 128 * 2);
    __half* A1h   = (__half*)alloc((size_t)N * 128 * 2);
    __half* H1h   = (__half*)alloc((size_t)N * 512 * 2);
    __half* t2    = (__half*)alloc((size_t)N * 128 * 2);
    __half* A3h   = (__half*)alloc((size_t)N * 128 * 2);
    __half* W1T   = (__half*)alloc((size_t)512 * 128 * 2);
    __half* W3T   = (__half*)alloc((size_t)128 * 512 * 2);
    __half* F1h   = (__half*)alloc((size_t)256 * 128 * 2);
    (void)ws_size; (void)n_in; (void)out_size;

    const int MB128 = (N + 127) / 128;  // 391
    const int NB = (N + 255) >> 8;      // 196
    dim3 blk(256);

    // 0) zero bucket counters
    hipMemsetAsync(bucket_cnt, 0, 257 * 4, stream);

    // 1) fused prep + bucket count
    k_prep_all<<<1024, blk, 0, stream>>>(x, W1, W3, fc1w, fc2b, dst, bucket_cnt,
                                         out, x16, W1T, W3T, F1h, N, E);

    // 2) bucket prefix
    k_bscan<<<1, blk, 0, stream>>>(bucket_cnt, bucket_base, bucket_cursor, rowptr, N, E);

    // 3) binning fill -> pairs
    k_bfill<<<(E + 4095) / 4096, blk, 0, stream>>>(src, dst, bucket_cursor, pairs, E);

    // 4) per-quarter local sort -> csr, rowptr, dinv (all coalesced)
    k_bsort<<<NB * 4, blk, 0, stream>>>(pairs, bucket_base, rowptr, dinv, csr, N);

    // 5) agg1 = Agg(x16) -> fp16 [N,128]
    k_gather<false><<<(N * 64 + 255) / 256, blk, 0, stream>>>(x16, rowptr, csr, dinv, nullptr, A1h, N);

    // 6) h1 = leaky(agg1 @ W1 + b1) -> fp16 [N,512]
    k_mgemm<1><<<MB128 * 4, blk, 0, stream>>>(A1h, W1T, b1, nullptr, H1h, N, 512, 128);

    // 7) t2 = h1 @ W3 -> fp16 [N,128]
    k_mgemm<0><<<MB128 * 1, blk, 0, stream>>>(H1h, W3T, nullptr, nullptr, t2, N, 128, 512);

    // 8) h2 = leaky(Agg(t2) + b3) -> fp16 [N,128]
    k_gather<true><<<(N * 64 + 255) / 256, blk, 0, stream>>>(t2, rowptr, csr, dinv, b3, A3h, N);

    // 9) out = leaky(h2 @ fc1_w^T + fc1_b) @ fc2_w^T + fc2_b  (fc2 fused, atomic partials)
    k_mgemm<2><<<MB128 * 2, blk, 0, stream>>>(A3h, F1h, fc1b, fc2w, out, N, 256, 128);
}

// Round 10
// 298.545 us; speedup vs baseline: 1.2651x; 1.1517x over previous
//
#include <hip/hip_runtime.h>
#include <hip/hip_fp16.h>

typedef _Float16 f16x8 __attribute__((ext_vector_type(8)));
typedef __attribute__((ext_vector_type(4))) float f32x4;

static __device__ __forceinline__ float leaky(float v) { return v >= 0.f ? v : 0.01f * v; }

// ---------------- fused prep: out init, x->fp16, B-fragment packing, bucket count --------
// Fragment layout (mfma_f32_16x16x32_f16 B-operand): frag[cb][ks][lane][j] = B[k][n],
//   n = cb*16 + (lane&15), k = ks*32 + (lane>>4)*8 + j   (validated by rdB pattern R5-R9)
__global__ __launch_bounds__(256) void k_prep_all(
    const float* __restrict__ x, const float* __restrict__ W1, const float* __restrict__ W3,
    const float* __restrict__ fc1w, const float* __restrict__ fc2b,
    const int* __restrict__ dst, int* __restrict__ bucket_cnt,
    float* __restrict__ out, __half* __restrict__ x16,
    _Float16* __restrict__ W1f, _Float16* __restrict__ W3f, _Float16* __restrict__ F1f,
    int N, int E)
{
    __shared__ int bcnt[256];
    bcnt[threadIdx.x] = 0;
    __syncthreads();
    const int gsz = gridDim.x * 256;
    const int gtid = blockIdx.x * 256 + threadIdx.x;
    float ob = fc2b[0];
    for (int i = gtid; i < N; i += gsz) out[i] = ob;
    // W1f: cb<32, ks<4  from W1 [128][512]
    for (int i = gtid; i < 32 * 4 * 64 * 8; i += gsz) {
        int j = i & 7, l = (i >> 3) & 63, ks = (i >> 9) & 3, cb = i >> 11;
        int k = ks * 32 + (l >> 4) * 8 + j, n = cb * 16 + (l & 15);
        W1f[i] = (_Float16)W1[k * 512 + n];
    }
    // W3f: cb<8, ks<16  from W3 [512][128]
    for (int i = gtid; i < 8 * 16 * 64 * 8; i += gsz) {
        int j = i & 7, l = (i >> 3) & 63, ks = (i >> 9) & 15, cb = i >> 13;
        int k = ks * 32 + (l >> 4) * 8 + j, n = cb * 16 + (l & 15);
        W3f[i] = (_Float16)W3[k * 128 + n];
    }
    // F1f: cb<16, ks<4  from fc1w [256][128] ([out][in]; B[k][n]=fc1w[n][k])
    for (int i = gtid; i < 16 * 4 * 64 * 8; i += gsz) {
        int j = i & 7, l = (i >> 3) & 63, ks = (i >> 9) & 3, cb = i >> 11;
        int k = ks * 32 + (l >> 4) * 8 + j, n = cb * 16 + (l & 15);
        F1f[i] = (_Float16)fc1w[n * 128 + k];
    }
    for (int i = gtid; i < N * 64; i += gsz) {
        float2 f = ((const float2*)x)[i];
        ((__half2*)x16)[i] = __floats2half2_rn(f.x, f.y);
    }
    for (int e = gtid; e < E; e += gsz) atomicAdd(&bcnt[dst[e] >> 8], 1);
    __syncthreads();
    int c = bcnt[threadIdx.x];
    if (c > 0) atomicAdd(&bucket_cnt[threadIdx.x], c);
}

// ---------------- bucket prefix (1 block) ----------------
__global__ __launch_bounds__(256) void k_bscan(const int* __restrict__ bucket_cnt,
                                               int* __restrict__ bucket_base,
                                               int* __restrict__ bucket_cursor,
                                               int* __restrict__ rowptr, int N, int E) {
    __shared__ int s[256];
    int tx = threadIdx.x;
    int v = bucket_cnt[tx];
    s[tx] = v; __syncthreads();
    for (int off = 1; off < 256; off <<= 1) {
        int t = (tx >= off) ? s[tx - off] : 0;
        __syncthreads();
        s[tx] += t;
        __syncthreads();
    }
    int excl = s[tx] - v;
    bucket_base[tx] = excl;
    bucket_cursor[tx] = excl;
    if (tx == 0) { bucket_base[256] = E; rowptr[N] = E; }
}

// ---------------- binning fill: pairs (dlocal<<24 | src) grouped by bucket ----------------
__global__ __launch_bounds__(256) void k_bfill(const int* __restrict__ src, const int* __restrict__ dst,
                                               int* __restrict__ bucket_cursor,
                                               unsigned int* __restrict__ pairs, int E) {
    __shared__ int cnt[256];
    __shared__ int base[256];
    const int CH = 4096;
    int c0 = blockIdx.x * CH;
    int cend = c0 + CH < E ? c0 + CH : E;
    int tx = threadIdx.x;
    cnt[tx] = 0;
    __syncthreads();
    for (int i = c0 + tx; i < cend; i += 256) atomicAdd(&cnt[dst[i] >> 8], 1);
    __syncthreads();
    int myc = cnt[tx];
    int mybase = 0;
    if (myc > 0) mybase = atomicAdd(&bucket_cursor[tx], myc);
    __syncthreads();
    cnt[tx] = 0;
    base[tx] = mybase;
    __syncthreads();
    for (int i = c0 + tx; i < cend; i += 256) {
        int d = dst[i];
        int b = d >> 8;
        int pos = base[b] + atomicAdd(&cnt[b], 1);
        pairs[pos] = ((unsigned)(d & 255) << 24) | (unsigned)src[i];
    }
}

// -------- per-quarter-bucket: local sort -> csr/rowptr/dinv + x16 pre-scale ----------
__global__ __launch_bounds__(256) void k_bsort(const unsigned int* __restrict__ pairs,
                                               const int* __restrict__ bucket_base,
                                               int* __restrict__ rowptr, float* __restrict__ dinv,
                                               int* __restrict__ csr, __half* __restrict__ x16,
                                               int N) {
    __shared__ int cnt[256], pre[256], cur[64];
    __shared__ float sdinv[256];
    __shared__ int stage[3072];
    const int B = blockIdx.x >> 2, q = blockIdx.x & 3;
    const int tx = threadIdx.x;
    const int pbase = bucket_base[B], pcnt = bucket_base[B + 1] - pbase;
    cnt[tx] = 0;
    __syncthreads();
    for (int i = tx; i < pcnt; i += 256) atomicAdd(&cnt[pairs[pbase + i] >> 24], 1);
    __syncthreads();
    int v = cnt[tx];
    pre[tx] = v; __syncthreads();
    for (int off = 1; off < 256; off <<= 1) {
        int t = (tx >= off) ? pre[tx - off] : 0;
        __syncthreads();
        pre[tx] += t;
        __syncthreads();
    }
    float dv = rsqrtf((float)v + 1.0f);
    sdinv[tx] = dv;
    int node = B * 256 + tx;
    if (node < N) {
        rowptr[node] = pbase + (pre[tx] - v);
        dinv[node] = dv;
    }
    const int d0 = q * 64;
    const int qstart = pre[d0] - cnt[d0];
    const int qcnt = pre[d0 + 63] - qstart;
    if (tx < 64) cur[tx] = (pre[d0 + tx] - cnt[d0 + tx]) - qstart;
    __syncthreads();
    if (qcnt > 0) {
        if (qcnt <= 3072) {
            for (int i = tx; i < pcnt; i += 256) {
                unsigned p = pairs[pbase + i];
                int dl = (int)(p >> 24) - d0;
                if ((unsigned)dl < 64u) {
                    int pos = atomicAdd(&cur[dl], 1);
                    stage[pos] = (int)(p & 0xFFFFFFu);
                }
            }
            __syncthreads();
            for (int i = tx; i < qcnt; i += 256) csr[pbase + qstart + i] = stage[i];
        } else {
            for (int i = tx; i < pcnt; i += 256) {
                unsigned p = pairs[pbase + i];
                int dl = (int)(p >> 24) - d0;
                if ((unsigned)dl < 64u) {
                    int pos = atomicAdd(&cur[dl], 1);
                    csr[pbase + qstart + pos] = (int)(p & 0xFFFFFFu);
                }
            }
        }
    }
    // pre-scale x16 rows [B*256 + q*64, +64) by their dinv
    for (int i = tx; i < 64 * 64; i += 256) {
        int r = i >> 6, c = i & 63;
        int nd = B * 256 + q * 64 + r;
        if (nd < N) {
            float s = sdinv[q * 64 + r];
            float2 f = __half22float2(((__half2*)x16)[nd * 64 + c]);
            ((__half2*)x16)[nd * 64 + c] = __floats2half2_rn(f.x * s, f.y * s);
        }
    }
}

// ---------------- gather: rows pre-scaled -> pure row-sum ----------------
// out[d] = act( dinv[d] * (X'[d] + sum_{s} X'[s]) + bias )
template <bool BIASACT>
__global__ __launch_bounds__(256) void k_gather(const __half* __restrict__ X,
                                                const int* __restrict__ rowptr,
                                                const int* __restrict__ csr,
                                                const float* __restrict__ dinv,
                                                const float* __restrict__ bias,
                                                __half* __restrict__ outp, int N) {
    int wid = __builtin_amdgcn_readfirstlane((int)((blockIdx.x * 256 + threadIdx.x) >> 6));
    if (wid >= N) return;
    int lane = threadIdx.x & 63, c = lane * 2;
    float di = dinv[wid];
    float2 self = __half22float2(*(const __half2*)(X + (size_t)wid * 128 + c));
    float accx = self.x, accy = self.y;
    int k = rowptr[wid], end = rowptr[wid + 1];
    for (; k < end; k += 8) {
        int ss[8];
        #pragma unroll
        for (int i = 0; i < 8; ++i) {
            int idx = k + i;
            ss[i] = (idx < end) ? csr[idx] : -1;
        }
        #pragma unroll
        for (int i = 0; i < 8; ++i) {
            if (ss[i] >= 0) {
                float2 f = __half22float2(*(const __half2*)(X + (size_t)ss[i] * 128 + c));
                accx += f.x;
                accy += f.y;
            }
        }
    }
    accx *= di;
    accy *= di;
    if (BIASACT) {
        accx = leaky(accx + bias[c]);
        accy = leaky(accy + bias[c + 1]);
    }
    *(__half2*)(outp + (size_t)wid * 128 + c) = __floats2half2_rn(accx, accy);
}

// ---------------- fused GEMM1+GEMM2: t2' = (leaky(A@W1+b1) @ W3) * dinv ----------------
// A: [M][128] fp16; W1f/W3f pre-packed fragments; out t2: [M][128] fp16 pre-scaled.
__global__ __launch_bounds__(256, 2) void k_fused12(
    const __half* __restrict__ A1h, const _Float16* __restrict__ W1f,
    const _Float16* __restrict__ W3f, const float* __restrict__ b1,
    const float* __restrict__ dinv, __half* __restrict__ t2, int M)
{
    __shared__ __align__(16) _Float16 As[128 * 136];
    __shared__ __align__(16) _Float16 Hs[128 * 136];
    const int tid = threadIdx.x, lane = tid & 63, wid = tid >> 6;
    const int wr = wid >> 1, wc = wid & 1;
    const int m0 = blockIdx.x * 128;
    // stage A tile [128][136]
    {
        const int r = tid >> 1, hf = tid & 1;
        int gr = m0 + r; if (gr >= M) gr = M - 1;
        const __half* Ar = A1h + (size_t)gr * 128;
        #pragma unroll
        for (int c = 0; c < 8; ++c) {
            int ch = hf * 8 + c;
            *(uint4*)(As + r * 136 + ch * 8) = *(const uint4*)(Ar + ch * 8);
        }
    }
    // bias preload (per-lane cols for each (q,n))
    float bq[4][4];
    #pragma unroll
    for (int q = 0; q < 4; ++q)
        #pragma unroll
        for (int n = 0; n < 4; ++n)
            bq[q][n] = b1[q * 128 + wc * 64 + n * 16 + (lane & 15)];
    __syncthreads();

    const int arow = lane & 15, kch = (lane >> 4) * 8;
    f32x4 acc2[4][4] = {};
    #pragma unroll
    for (int q = 0; q < 4; ++q) {
        f32x4 acc1[4][4] = {};
        #pragma unroll
        for (int ks = 0; ks < 4; ++ks) {
            f16x8 af[4], bf[4];
            #pragma unroll
            for (int i = 0; i < 4; ++i)
                af[i] = *(const f16x8*)(As + (wr * 64 + i * 16 + arow) * 136 + ks * 32 + kch);
            #pragma unroll
            for (int n = 0; n < 4; ++n) {
                int cb = q * 8 + wc * 4 + n;
                bf[n] = *(const f16x8*)(W1f + ((size_t)(cb * 4 + ks) * 64 + lane) * 8);
            }
            #pragma unroll
            for (int i = 0; i < 4; ++i)
                #pragma unroll
                for (int n = 0; n < 4; ++n)
                    acc1[i][n] = __builtin_amdgcn_mfma_f32_16x16x32_f16(af[i], bf[n], acc1[i][n], 0, 0, 0);
        }
        __syncthreads();   // prev GEMM2 reads of Hs done (all waves past it)
        #pragma unroll
        for (int i = 0; i < 4; ++i)
            #pragma unroll
            for (int n = 0; n < 4; ++n)
                #pragma unroll
                for (int j = 0; j < 4; ++j) {
                    int row = wr * 64 + i * 16 + (lane >> 4) * 4 + j;
                    int col = wc * 64 + n * 16 + (lane & 15);
                    Hs[row * 136 + col] = (_Float16)leaky(acc1[i][n][j] + bq[q][n]);
                }
        __syncthreads();
        #pragma unroll
        for (int ks = 0; ks < 4; ++ks) {
            f16x8 af[4], bf[4];
            #pragma unroll
            for (int i = 0; i < 4; ++i)
                af[i] = *(const f16x8*)(Hs + (wr * 64 + i * 16 + arow) * 136 + ks * 32 + kch);
            #pragma unroll
            for (int n = 0; n < 4; ++n) {
                int cb = wc * 4 + n, ksg = q * 4 + ks;
                bf[n] = *(const f16x8*)(W3f + ((size_t)(cb * 16 + ksg) * 64 + lane) * 8);
            }
            #pragma unroll
            for (int i = 0; i < 4; ++i)
                #pragma unroll
                for (int n = 0; n < 4; ++n)
                    acc2[i][n] = __builtin_amdgcn_mfma_f32_16x16x32_f16(af[i], bf[n], acc2[i][n], 0, 0, 0);
        }
    }
    // epilogue: deposit t2*dinv to Hs, coalesced copy out
    __syncthreads();
    #pragma unroll
    for (int i = 0; i < 4; ++i)
        #pragma unroll
        for (int j = 0; j < 4; ++j) {
            int row = wr * 64 + i * 16 + (lane >> 4) * 4 + j;
            int gr = m0 + row;
            float dv = dinv[gr < M ? gr : M - 1];
            #pragma unroll
            for (int n = 0; n < 4; ++n) {
                int col = wc * 64 + n * 16 + (lane & 15);
                Hs[row * 136 + col] = (_Float16)(acc2[i][n][j] * dv);
            }
        }
    __syncthreads();
    {
        const int r = tid >> 1, hf = tid & 1;
        int gr = m0 + r;
        if (gr < M) {
            #pragma unroll
            for (int c = 0; c < 8; ++c) {
                int ch = hf * 8 + c;
                *(uint4*)(t2 + (size_t)gr * 128 + ch * 8) = *(const uint4*)(Hs + r * 136 + ch * 8);
            }
        }
    }
}

// ---------------- GEMM3 + fc2 dot: out[row] += sum_col leaky(A@fc1wT+b)[col]*w2[col] -------
__global__ __launch_bounds__(256, 2) void k_fgemm3(
    const __half* __restrict__ A3h, const _Float16* __restrict__ F1f,
    const float* __restrict__ fc1b, const float* __restrict__ fc2w,
    float* __restrict__ out, int M)
{
    __shared__ __align__(16) _Float16 As[128 * 136];
    const int tid = threadIdx.x, lane = tid & 63, wid = tid >> 6;
    const int wr = wid >> 1, wc = wid & 1;
    const int bx = blockIdx.x & 1, m0 = (blockIdx.x >> 1) * 128;
    const int nbase = bx * 128;
    {
        const int r = tid >> 1, hf = tid & 1;
        int gr = m0 + r; if (gr >= M) gr = M - 1;
        const __half* Ar = A3h + (size_t)gr * 128;
        #pragma unroll
        for (int c = 0; c < 8; ++c) {
            int ch = hf * 8 + c;
            *(uint4*)(As + r * 136 + ch * 8) = *(const uint4*)(Ar + ch * 8);
        }
    }
    __syncthreads();
    const int arow = lane & 15, kch = (lane >> 4) * 8;
    f32x4 acc[4][4] = {};
    #pragma unroll
    for (int ks = 0; ks < 4; ++ks) {
        f16x8 af[4], bf[4];
        #pragma unroll
        for (int i = 0; i < 4; ++i)
            af[i] = *(const f16x8*)(As + (wr * 64 + i * 16 + arow) * 136 + ks * 32 + kch);
        #pragma unroll
        for (int n = 0; n < 4; ++n) {
            int cb = bx * 8 + wc * 4 + n;
            bf[n] = *(const f16x8*)(F1f + ((size_t)(cb * 4 + ks) * 64 + lane) * 8);
        }
        #pragma unroll
        for (int i = 0; i < 4; ++i)
            #pragma unroll
            for (int n = 0; n < 4; ++n)
                acc[i][n] = __builtin_amdgcn_mfma_f32_16x16x32_f16(af[i], bf[n], acc[i][n], 0, 0, 0);
    }
    #pragma unroll
    for (int i = 0; i < 4; ++i)
        #pragma unroll
        for (int j = 0; j < 4; ++j) {
            int row = m0 + wr * 64 + i * 16 + (lane >> 4) * 4 + j;
            float s = 0.f;
            #pragma unroll
            for (int n = 0; n < 4; ++n) {
                int col = nbase + wc * 64 + n * 16 + (lane & 15);
                float v = leaky(acc[i][n][j] + fc1b[col]);
                s += v * fc2w[col];
            }
            s += __shfl_xor(s, 8);
            s += __shfl_xor(s, 4);
            s += __shfl_xor(s, 2);
            s += __shfl_xor(s, 1);
            if ((lane & 15) == 0 && row < M) atomicAdd(&out[row], s);
        }
}

extern "C" void kernel_launch(void* const* d_in, const int* in_sizes, int n_in,
                              void* d_out, int out_size, void* d_ws, size_t ws_size,
                              hipStream_t stream) {
    const float* x    = (const float*)d_in[0];
    const int*   ei   = (const int*)d_in[1];
    const float* W1   = (const float*)d_in[2];
    const float* b1   = (const float*)d_in[3];
    const float* W3   = (const float*)d_in[4];
    const float* b3   = (const float*)d_in[5];
    const float* fc1w = (const float*)d_in[6];
    const float* fc1b = (const float*)d_in[7];
    const float* fc2w = (const float*)d_in[8];
    const float* fc2b = (const float*)d_in[9];
    float* out = (float*)d_out;

    int N = in_sizes[0] / 128;   // 50000
    int E = in_sizes[1] / 2;     // 800000
    const int* src = ei;
    const int* dst = ei + E;

    char* ws = (char*)d_ws;
    size_t off = 0;
    auto alloc = [&](size_t bytes) { void* p = ws + off; off += (bytes + 255) & ~255ull; return p; };
    int*   bucket_cnt    = (int*)alloc(257 * 4);
    int*   bucket_base   = (int*)alloc(257 * 4);
    int*   bucket_cursor = (int*)alloc(257 * 4);
    int*   rowptr = (int*)alloc((size_t)(N + 1) * 4);
    unsigned int* pairs = (unsigned int*)alloc((size_t)E * 4);
    int*   csr    = (int*)alloc((size_t)E * 4);
    float* dinv   = (float*)alloc((size_t)N * 4);
    __half* x16   = (__half*)alloc((size_t)N * 128 * 2);
    __half* A1h   = (__half*)alloc((size_t)N * 128 * 2);
    __half* t2    = (__half*)alloc((size_t)N * 128 * 2);
    __half* A3h   = (__half*)alloc((size_t)N * 128 * 2);
    _Float16* W1f = (_Float16*)alloc((size_t)32 * 4 * 64 * 8 * 2);
    _Float16* W3f = (_Float16*)alloc((size_t)8 * 16 * 64 * 8 * 2);
    _Float16* F1f = (_Float16*)alloc((size_t)16 * 4 * 64 * 8 * 2);
    (void)ws_size; (void)n_in; (void)out_size;

    const int MB128 = (N + 127) / 128;  // 391
    const int NB = (N + 255) >> 8;      // 196
    dim3 blk(256);

    hipMemsetAsync(bucket_cnt, 0, 257 * 4, stream);

    // 1) prep: out init, x16, fragment packs, bucket count
    k_prep_all<<<1024, blk, 0, stream>>>(x, W1, W3, fc1w, fc2b, dst, bucket_cnt,
                                         out, x16, W1f, W3f, F1f, N, E);
    // 2) bucket prefix
    k_bscan<<<1, blk, 0, stream>>>(bucket_cnt, bucket_base, bucket_cursor, rowptr, N, E);
    // 3) binning fill
    k_bfill<<<(E + 4095) / 4096, blk, 0, stream>>>(src, dst, bucket_cursor, pairs, E);
    // 4) sort -> csr/rowptr/dinv + x16 pre-scale
    k_bsort<<<NB * 4, blk, 0, stream>>>(pairs, bucket_base, rowptr, dinv, csr, x16, N);
    // 5) agg1' = dinv*(rowsum of x16') -> A1h
    k_gather<false><<<(N * 64 + 255) / 256, blk, 0, stream>>>(x16, rowptr, csr, dinv, nullptr, A1h, N);
    // 6) t2' = (leaky(A1h@W1+b1)@W3)*dinv  (h1 never leaves the CU)
    k_fused12<<<MB128, blk, 0, stream>>>(A1h, W1f, W3f, b1, dinv, t2, N);
    // 7) h2 = leaky(dinv*rowsum(t2') + b3) -> A3h
    k_gather<true><<<(N * 64 + 255) / 256, blk, 0, stream>>>(t2, rowptr, csr, dinv, b3, A3h, N);
    // 8) out = leaky(A3h@fc1_w^T+fc1_b)@fc2_w^T + fc2_b
    k_fgemm3<<<MB128 * 2, blk, 0, stream>>>(A3h, F1f, fc1b, fc2w, out, N);
}

// Round 11
// 246.777 us; speedup vs baseline: 1.5305x; 1.2098x over previous
//
#include <hip/hip_runtime.h>
#include <hip/hip_fp16.h>

typedef _Float16 f16x8 __attribute__((ext_vector_type(8)));
typedef __attribute__((ext_vector_type(4))) float f32x4;

static __device__ __forceinline__ float leaky(float v) { return v >= 0.f ? v : 0.01f * v; }

// ---------------- fused prep: out init, x->fp16, zero rows, B-fragment packing, bucket count
__global__ __launch_bounds__(256) void k_prep_all(
    const float* __restrict__ x, const float* __restrict__ W1, const float* __restrict__ W3,
    const float* __restrict__ fc1w, const float* __restrict__ fc2b,
    const int* __restrict__ dst, int* __restrict__ bucket_cnt,
    float* __restrict__ out, __half* __restrict__ x16, __half* __restrict__ t2,
    _Float16* __restrict__ W1f, _Float16* __restrict__ W3f, _Float16* __restrict__ F1f,
    int N, int E)
{
    __shared__ int bcnt[256];
    bcnt[threadIdx.x] = 0;
    __syncthreads();
    const int gsz = gridDim.x * 256;
    const int gtid = blockIdx.x * 256 + threadIdx.x;
    float ob = fc2b[0];
    for (int i = gtid; i < N; i += gsz) out[i] = ob;
    // zero phantom row N of x16 and t2
    for (int i = gtid; i < 64; i += gsz) {
        ((__half2*)x16)[(size_t)N * 64 + i] = __floats2half2_rn(0.f, 0.f);
        ((__half2*)t2)[(size_t)N * 64 + i] = __floats2half2_rn(0.f, 0.f);
    }
    // W1f: cb<32, ks<4  from W1 [128][512]
    for (int i = gtid; i < 32 * 4 * 64 * 8; i += gsz) {
        int j = i & 7, l = (i >> 3) & 63, ks = (i >> 9) & 3, cb = i >> 11;
        int k = ks * 32 + (l >> 4) * 8 + j, n = cb * 16 + (l & 15);
        W1f[i] = (_Float16)W1[k * 512 + n];
    }
    // W3f: cb<8, ks<16  from W3 [512][128]
    for (int i = gtid; i < 8 * 16 * 64 * 8; i += gsz) {
        int j = i & 7, l = (i >> 3) & 63, ks = (i >> 9) & 15, cb = i >> 13;
        int k = ks * 32 + (l >> 4) * 8 + j, n = cb * 16 + (l & 15);
        W3f[i] = (_Float16)W3[k * 128 + n];
    }
    // F1f: cb<16, ks<4  from fc1w [256][128]
    for (int i = gtid; i < 16 * 4 * 64 * 8; i += gsz) {
        int j = i & 7, l = (i >> 3) & 63, ks = (i >> 9) & 3, cb = i >> 11;
        int k = ks * 32 + (l >> 4) * 8 + j, n = cb * 16 + (l & 15);
        F1f[i] = (_Float16)fc1w[n * 128 + k];
    }
    for (int i = gtid; i < N * 64; i += gsz) {
        float2 f = ((const float2*)x)[i];
        ((__half2*)x16)[i] = __floats2half2_rn(f.x, f.y);
    }
    for (int e = gtid; e < E; e += gsz) atomicAdd(&bcnt[dst[e] >> 8], 1);
    __syncthreads();
    int c = bcnt[threadIdx.x];
    if (c > 0) atomicAdd(&bucket_cnt[threadIdx.x], c);
}

// ---------------- bucket prefix (1 block) ----------------
__global__ __launch_bounds__(256) void k_bscan(const int* __restrict__ bucket_cnt,
                                               int* __restrict__ bucket_base,
                                               int* __restrict__ bucket_cursor, int E) {
    __shared__ int s[256];
    int tx = threadIdx.x;
    int v = bucket_cnt[tx];
    s[tx] = v; __syncthreads();
    for (int off = 1; off < 256; off <<= 1) {
        int t = (tx >= off) ? s[tx - off] : 0;
        __syncthreads();
        s[tx] += t;
        __syncthreads();
    }
    int excl = s[tx] - v;
    bucket_base[tx] = excl;
    bucket_cursor[tx] = excl;
    if (tx == 0) bucket_base[256] = E;
}

// ---------------- binning fill: pairs (dlocal<<24 | src) grouped by bucket ----------------
__global__ __launch_bounds__(256) void k_bfill(const int* __restrict__ src, const int* __restrict__ dst,
                                               int* __restrict__ bucket_cursor,
                                               unsigned int* __restrict__ pairs, int E) {
    __shared__ int cnt[256];
    __shared__ int base[256];
    const int CH = 4096;
    int c0 = blockIdx.x * CH;
    int cend = c0 + CH < E ? c0 + CH : E;
    int tx = threadIdx.x;
    cnt[tx] = 0;
    __syncthreads();
    for (int i = c0 + tx; i < cend; i += 256) atomicAdd(&cnt[dst[i] >> 8], 1);
    __syncthreads();
    int myc = cnt[tx];
    int mybase = 0;
    if (myc > 0) mybase = atomicAdd(&bucket_cursor[tx], myc);
    __syncthreads();
    cnt[tx] = 0;
    base[tx] = mybase;
    __syncthreads();
    for (int i = c0 + tx; i < cend; i += 256) {
        int d = dst[i];
        int b = d >> 8;
        int pos = base[b] + atomicAdd(&cnt[b], 1);
        pairs[pos] = ((unsigned)(d & 255) << 24) | (unsigned)src[i];
    }
}

// -------- per-quarter-bucket: padded CSR (self-in-list, pad=zero-row N) + desc + x16 prescale
__global__ __launch_bounds__(256) void k_bsort(const unsigned int* __restrict__ pairs,
                                               const int* __restrict__ bucket_base,
                                               uint4* __restrict__ desc, float* __restrict__ dinv,
                                               int* __restrict__ csr, __half* __restrict__ x16,
                                               int N) {
    __shared__ int cnt[256], pre[256], cur[64];
    __shared__ float sdinv[256];
    __shared__ int stage[3584];
    const int B = blockIdx.x >> 2, q = blockIdx.x & 3;
    const int tx = threadIdx.x;
    const int pbase = bucket_base[B], pcnt = bucket_base[B + 1] - pbase;
    const int PB = pbase + B * 2048;   // padded bucket base
    cnt[tx] = 0;
    __syncthreads();
    for (int i = tx; i < pcnt; i += 256) atomicAdd(&cnt[pairs[pbase + i] >> 24], 1);
    __syncthreads();
    int deg = cnt[tx];
    int cnt8 = (deg + 8) & ~7;               // (deg + 1 self) rounded up to 8
    float dv = rsqrtf((float)deg + 1.0f);
    __syncthreads();
    cnt[tx] = cnt8;
    sdinv[tx] = dv;
    pre[tx] = cnt8;
    __syncthreads();
    for (int off = 1; off < 256; off <<= 1) {
        int t = (tx >= off) ? pre[tx - off] : 0;
        __syncthreads();
        pre[tx] += t;
        __syncthreads();
    }
    int excl = pre[tx] - cnt8;
    int node = B * 256 + tx;
    if (node < N) {
        desc[node] = make_uint4((unsigned)(PB + excl), (unsigned)(cnt8 >> 3),
                                __float_as_uint(dv), 0u);
        dinv[node] = dv;
    }
    __syncthreads();
    pre[tx] = excl;
    __syncthreads();
    const int d0 = q * 64;
    const int qstart8 = pre[d0];
    const int qcnt8 = pre[d0 + 63] + cnt[d0 + 63] - qstart8;
    if (tx < 64) cur[tx] = pre[d0 + tx] - qstart8 + 1;   // slot 0 reserved for self
    __syncthreads();
    if (qcnt8 <= 3584) {
        for (int i = tx; i < qcnt8; i += 256) stage[i] = N;   // zero-row pads
        __syncthreads();
        if (tx < 64) stage[pre[d0 + tx] - qstart8] = B * 256 + d0 + tx;   // self first
        for (int i = tx; i < pcnt; i += 256) {
            unsigned p = pairs[pbase + i];
            int dl = (int)(p >> 24) - d0;
            if ((unsigned)dl < 64u) {
                int pos = atomicAdd(&cur[dl], 1);
                stage[pos] = (int)(p & 0xFFFFFFu);
            }
        }
        __syncthreads();
        for (int i = tx; i < qcnt8; i += 256) csr[PB + qstart8 + i] = stage[i];
    } else {
        for (int i = tx; i < qcnt8; i += 256) csr[PB + qstart8 + i] = N;
        __syncthreads();
        if (tx < 64) csr[PB + pre[d0 + tx]] = B * 256 + d0 + tx;
        for (int i = tx; i < pcnt; i += 256) {
            unsigned p = pairs[pbase + i];
            int dl = (int)(p >> 24) - d0;
            if ((unsigned)dl < 64u) {
                int pos = atomicAdd(&cur[dl], 1);
                csr[PB + qstart8 + pos] = (int)(p & 0xFFFFFFu);
            }
        }
    }
    // pre-scale x16 rows [B*256 + q*64, +64) by their dinv
    for (int i = tx; i < 64 * 64; i += 256) {
        int r = i >> 6, c = i & 63;
        int nd = B * 256 + q * 64 + r;
        if (nd < N) {
            float s = sdinv[q * 64 + r];
            float2 f = __half22float2(((__half2*)x16)[(size_t)nd * 64 + c]);
            ((__half2*)x16)[(size_t)nd * 64 + c] = __floats2half2_rn(f.x * s, f.y * s);
        }
    }
}

// ---------------- gather: desc-driven, branch-free 8-wide, self in list ----------------
template <bool BIASACT>
__global__ __launch_bounds__(256) void k_gather(const __half* __restrict__ X,
                                                const uint4* __restrict__ desc,
                                                const int* __restrict__ csr,
                                                const float* __restrict__ bias,
                                                __half* __restrict__ outp, int N) {
    int wid = __builtin_amdgcn_readfirstlane((int)((blockIdx.x * 256 + threadIdx.x) >> 6));
    if (wid >= N) return;
    int lane = threadIdx.x & 63, c = lane * 2;
    uint4 d = desc[wid];
    int k0 = __builtin_amdgcn_readfirstlane((int)d.x);
    int nit = __builtin_amdgcn_readfirstlane((int)d.y);
    float di = __uint_as_float(d.z);
    float accx = 0.f, accy = 0.f;
    for (int it = 0; it < nit; ++it) {
        int kk = k0 + it * 8;
        int ss[8];
        #pragma unroll
        for (int i = 0; i < 8; ++i) ss[i] = csr[kk + i];
        #pragma unroll
        for (int i = 0; i < 8; ++i) {
            float2 f = __half22float2(*(const __half2*)(X + (size_t)ss[i] * 128 + c));
            accx += f.x;
            accy += f.y;
        }
    }
    accx *= di;
    accy *= di;
    if (BIASACT) {
        accx = leaky(accx + bias[c]);
        accy = leaky(accy + bias[c + 1]);
    }
    *(__half2*)(outp + (size_t)wid * 128 + c) = __floats2half2_rn(accx, accy);
}

// ---------------- fused GEMM1+GEMM2: t2' = (leaky(A@W1+b1) @ W3) * dinv ----------------
__global__ __launch_bounds__(256, 2) void k_fused12(
    const __half* __restrict__ A1h, const _Float16* __restrict__ W1f,
    const _Float16* __restrict__ W3f, const float* __restrict__ b1,
    const float* __restrict__ dinv, __half* __restrict__ t2, int M)
{
    __shared__ __align__(16) _Float16 As[128 * 136];
    __shared__ __align__(16) _Float16 Hs[128 * 136];
    const int tid = threadIdx.x, lane = tid & 63, wid = tid >> 6;
    const int wr = wid >> 1, wc = wid & 1;
    const int m0 = blockIdx.x * 128;
    {
        const int r = tid >> 1, hf = tid & 1;
        int gr = m0 + r; if (gr >= M) gr = M - 1;
        const __half* Ar = A1h + (size_t)gr * 128;
        #pragma unroll
        for (int c = 0; c < 8; ++c) {
            int ch = hf * 8 + c;
            *(uint4*)(As + r * 136 + ch * 8) = *(const uint4*)(Ar + ch * 8);
        }
    }
    float bq[4][4];
    #pragma unroll
    for (int q = 0; q < 4; ++q)
        #pragma unroll
        for (int n = 0; n < 4; ++n)
            bq[q][n] = b1[q * 128 + wc * 64 + n * 16 + (lane & 15)];
    __syncthreads();

    const int arow = lane & 15, kch = (lane >> 4) * 8;
    f32x4 acc2[4][4] = {};
    #pragma unroll
    for (int q = 0; q < 4; ++q) {
        f32x4 acc1[4][4] = {};
        #pragma unroll
        for (int ks = 0; ks < 4; ++ks) {
            f16x8 af[4], bf[4];
            #pragma unroll
            for (int i = 0; i < 4; ++i)
                af[i] = *(const f16x8*)(As + (wr * 64 + i * 16 + arow) * 136 + ks * 32 + kch);
            #pragma unroll
            for (int n = 0; n < 4; ++n) {
                int cb = q * 8 + wc * 4 + n;
                bf[n] = *(const f16x8*)(W1f + ((size_t)(cb * 4 + ks) * 64 + lane) * 8);
            }
            #pragma unroll
            for (int i = 0; i < 4; ++i)
                #pragma unroll
                for (int n = 0; n < 4; ++n)
                    acc1[i][n] = __builtin_amdgcn_mfma_f32_16x16x32_f16(af[i], bf[n], acc1[i][n], 0, 0, 0);
        }
        __syncthreads();
        #pragma unroll
        for (int i = 0; i < 4; ++i)
            #pragma unroll
            for (int n = 0; n < 4; ++n)
                #pragma unroll
                for (int j = 0; j < 4; ++j) {
                    int row = wr * 64 + i * 16 + (lane >> 4) * 4 + j;
                    int col = wc * 64 + n * 16 + (lane & 15);
                    Hs[row * 136 + col] = (_Float16)leaky(acc1[i][n][j] + bq[q][n]);
                }
        __syncthreads();
        #pragma unroll
        for (int ks = 0; ks < 4; ++ks) {
            f16x8 af[4], bf[4];
            #pragma unroll
            for (int i = 0; i < 4; ++i)
                af[i] = *(const f16x8*)(Hs + (wr * 64 + i * 16 + arow) * 136 + ks * 32 + kch);
            #pragma unroll
            for (int n = 0; n < 4; ++n) {
                int cb = wc * 4 + n, ksg = q * 4 + ks;
                bf[n] = *(const f16x8*)(W3f + ((size_t)(cb * 16 + ksg) * 64 + lane) * 8);
            }
            #pragma unroll
            for (int i = 0; i < 4; ++i)
                #pragma unroll
                for (int n = 0; n < 4; ++n)
                    acc2[i][n] = __builtin_amdgcn_mfma_f32_16x16x32_f16(af[i], bf[n], acc2[i][n], 0, 0, 0);
        }
    }
    __syncthreads();
    #pragma unroll
    for (int i = 0; i < 4; ++i)
        #pragma unroll
        for (int j = 0; j < 4; ++j) {
            int row = wr * 64 + i * 16 + (lane >> 4) * 4 + j;
            int gr = m0 + row;
            float dv = dinv[gr < M ? gr : M - 1];
            #pragma unroll
            for (int n = 0; n < 4; ++n) {
                int col = wc * 64 + n * 16 + (lane & 15);
                Hs[row * 136 + col] = (_Float16)(acc2[i][n][j] * dv);
            }
        }
    __syncthreads();
    {
        const int r = tid >> 1, hf = tid & 1;
        int gr = m0 + r;
        if (gr < M) {
            #pragma unroll
            for (int c = 0; c < 8; ++c) {
                int ch = hf * 8 + c;
                *(uint4*)(t2 + (size_t)gr * 128 + ch * 8) = *(const uint4*)(Hs + r * 136 + ch * 8);
            }
        }
    }
}

// ---------------- GEMM3 + fc2 dot ----------------
__global__ __launch_bounds__(256, 2) void k_fgemm3(
    const __half* __restrict__ A3h, const _Float16* __restrict__ F1f,
    const float* __restrict__ fc1b, const float* __restrict__ fc2w,
    float* __restrict__ out, int M)
{
    __shared__ __align__(16) _Float16 As[128 * 136];
    const int tid = threadIdx.x, lane = tid & 63, wid = tid >> 6;
    const int wr = wid >> 1, wc = wid & 1;
    const int bx = blockIdx.x & 1, m0 = (blockIdx.x >> 1) * 128;
    const int nbase = bx * 128;
    {
        const int r = tid >> 1, hf = tid & 1;
        int gr = m0 + r; if (gr >= M) gr = M - 1;
        const __half* Ar = A3h + (size_t)gr * 128;
        #pragma unroll
        for (int c = 0; c < 8; ++c) {
            int ch = hf * 8 + c;
            *(uint4*)(As + r * 136 + ch * 8) = *(const uint4*)(Ar + ch * 8);
        }
    }
    __syncthreads();
    const int arow = lane & 15, kch = (lane >> 4) * 8;
    f32x4 acc[4][4] = {};
    #pragma unroll
    for (int ks = 0; ks < 4; ++ks) {
        f16x8 af[4], bf[4];
        #pragma unroll
        for (int i = 0; i < 4; ++i)
            af[i] = *(const f16x8*)(As + (wr * 64 + i * 16 + arow) * 136 + ks * 32 + kch);
        #pragma unroll
        for (int n = 0; n < 4; ++n) {
            int cb = bx * 8 + wc * 4 + n;
            bf[n] = *(const f16x8*)(F1f + ((size_t)(cb * 4 + ks) * 64 + lane) * 8);
        }
        #pragma unroll
        for (int i = 0; i < 4; ++i)
            #pragma unroll
            for (int n = 0; n < 4; ++n)
                acc[i][n] = __builtin_amdgcn_mfma_f32_16x16x32_f16(af[i], bf[n], acc[i][n], 0, 0, 0);
    }
    #pragma unroll
    for (int i = 0; i < 4; ++i)
        #pragma unroll
        for (int j = 0; j < 4; ++j) {
            int row = m0 + wr * 64 + i * 16 + (lane >> 4) * 4 + j;
            float s = 0.f;
            #pragma unroll
            for (int n = 0; n < 4; ++n) {
                int col = nbase + wc * 64 + n * 16 + (lane & 15);
                float v = leaky(acc[i][n][j] + fc1b[col]);
                s += v * fc2w[col];
            }
            s += __shfl_xor(s, 8);
            s += __shfl_xor(s, 4);
            s += __shfl_xor(s, 2);
            s += __shfl_xor(s, 1);
            if ((lane & 15) == 0 && row < M) atomicAdd(&out[row], s);
        }
}

extern "C" void kernel_launch(void* const* d_in, const int* in_sizes, int n_in,
                              void* d_out, int out_size, void* d_ws, size_t ws_size,
                              hipStream_t stream) {
    const float* x    = (const float*)d_in[0];
    const int*   ei   = (const int*)d_in[1];
    const float* W1   = (const float*)d_in[2];
    const float* b1   = (const float*)d_in[3];
    const float* W3   = (const float*)d_in[4];
    const float* b3   = (const float*)d_in[5];
    const float* fc1w = (const float*)d_in[6];
    const float* fc1b = (const float*)d_in[7];
    const float* fc2w = (const float*)d_in[8];
    const float* fc2b = (const float*)d_in[9];
    float* out = (float*)d_out;

    int N = in_sizes[0] / 128;   // 50000
    int E = in_sizes[1] / 2;     // 800000
    const int* src = ei;
    const int* dst = ei + E;

    const int NB = (N + 255) >> 8;      // 196
    char* ws = (char*)d_ws;
    size_t off = 0;
    auto alloc = [&](size_t bytes) { void* p = ws + off; off += (bytes + 255) & ~255ull; return p; };
    int*   bucket_cnt    = (int*)alloc(257 * 4);
    int*   bucket_base   = (int*)alloc(257 * 4);
    int*   bucket_cursor = (int*)alloc(257 * 4);
    uint4* desc   = (uint4*)alloc((size_t)N * 16);
    unsigned int* pairs = (unsigned int*)alloc((size_t)E * 4);
    int*   csr    = (int*)alloc(((size_t)E + (size_t)NB * 2048) * 4);
    float* dinv   = (float*)alloc((size_t)N * 4);
    __half* x16   = (__half*)alloc((size_t)(N + 1) * 128 * 2);
    __half* A1h   = (__half*)alloc((size_t)N * 128 * 2);
    __half* t2    = (__half*)alloc((size_t)(N + 1) * 128 * 2);
    __half* A3h   = (__half*)alloc((size_t)N * 128 * 2);
    _Float16* W1f = (_Float16*)alloc((size_t)32 * 4 * 64 * 8 * 2);
    _Float16* W3f = (_Float16*)alloc((size_t)8 * 16 * 64 * 8 * 2);
    _Float16* F1f = (_Float16*)alloc((size_t)16 * 4 * 64 * 8 * 2);
    (void)ws_size; (void)n_in; (void)out_size;

    const int MB128 = (N + 127) / 128;  // 391
    dim3 blk(256);

    hipMemsetAsync(bucket_cnt, 0, 257 * 4, stream);

    // 1) prep
    k_prep_all<<<1024, blk, 0, stream>>>(x, W1, W3, fc1w, fc2b, dst, bucket_cnt,
                                         out, x16, t2, W1f, W3f, F1f, N, E);
    // 2) bucket prefix
    k_bscan<<<1, blk, 0, stream>>>(bucket_cnt, bucket_base, bucket_cursor, E);
    // 3) binning fill
    k_bfill<<<(E + 4095) / 4096, blk, 0, stream>>>(src, dst, bucket_cursor, pairs, E);
    // 4) padded CSR + desc + dinv + x16 prescale
    k_bsort<<<NB * 4, blk, 0, stream>>>(pairs, bucket_base, desc, dinv, csr, x16, N);
    // 5) agg1' -> A1h
    k_gather<false><<<(N * 64 + 255) / 256, blk, 0, stream>>>(x16, desc, csr, nullptr, A1h, N);
    // 6) t2' = (leaky(A1h@W1+b1)@W3)*dinv
    k_fused12<<<MB128, blk, 0, stream>>>(A1h, W1f, W3f, b1, dinv, t2, N);
    // 7) h2 -> A3h
    k_gather<true><<<(N * 64 + 255) / 256, blk, 0, stream>>>(t2, desc, csr, b3, A3h, N);
    // 8) out
    k_fgemm3<<<MB128 * 2, blk, 0, stream>>>(A3h, F1f, fc1b, fc2w, out, N);
}

// Round 12
// 245.177 us; speedup vs baseline: 1.5405x; 1.0065x over previous
//
#include <hip/hip_runtime.h>
#include <hip/hip_fp16.h>

typedef _Float16 f16x8 __attribute__((ext_vector_type(8)));
typedef __attribute__((ext_vector_type(4))) float f32x4;

static __device__ __forceinline__ float leaky(float v) { return v >= 0.f ? v : 0.01f * v; }

// ---------------- fused prep: out init, x->fp16, zero rows, B-fragment packing, bucket count
__global__ __launch_bounds__(256) void k_prep_all(
    const float* __restrict__ x, const float* __restrict__ W1, const float* __restrict__ W3,
    const float* __restrict__ fc1w, const float* __restrict__ fc2b,
    const int* __restrict__ dst, int* __restrict__ bucket_cnt,
    float* __restrict__ out, __half* __restrict__ x16, __half* __restrict__ t2,
    _Float16* __restrict__ W1f, _Float16* __restrict__ W3f, _Float16* __restrict__ F1f,
    int N, int E)
{
    __shared__ int bcnt[256];
    bcnt[threadIdx.x] = 0;
    __syncthreads();
    const int gsz = gridDim.x * 256;
    const int gtid = blockIdx.x * 256 + threadIdx.x;
    float ob = fc2b[0];
    for (int i = gtid; i < N; i += gsz) out[i] = ob;
    for (int i = gtid; i < 64; i += gsz) {
        ((__half2*)x16)[(size_t)N * 64 + i] = __floats2half2_rn(0.f, 0.f);
        ((__half2*)t2)[(size_t)N * 64 + i] = __floats2half2_rn(0.f, 0.f);
    }
    // W1f: cb<32, ks<4  from W1 [128][512]
    for (int i = gtid; i < 32 * 4 * 64 * 8; i += gsz) {
        int j = i & 7, l = (i >> 3) & 63, ks = (i >> 9) & 3, cb = i >> 11;
        int k = ks * 32 + (l >> 4) * 8 + j, n = cb * 16 + (l & 15);
        W1f[i] = (_Float16)W1[k * 512 + n];
    }
    // W3f: cb<8, ks<16  from W3 [512][128]
    for (int i = gtid; i < 8 * 16 * 64 * 8; i += gsz) {
        int j = i & 7, l = (i >> 3) & 63, ks = (i >> 9) & 15, cb = i >> 13;
        int k = ks * 32 + (l >> 4) * 8 + j, n = cb * 16 + (l & 15);
        W3f[i] = (_Float16)W3[k * 128 + n];
    }
    // F1f: cb<16, ks<4  from fc1w [256][128]
    for (int i = gtid; i < 16 * 4 * 64 * 8; i += gsz) {
        int j = i & 7, l = (i >> 3) & 63, ks = (i >> 9) & 3, cb = i >> 11;
        int k = ks * 32 + (l >> 4) * 8 + j, n = cb * 16 + (l & 15);
        F1f[i] = (_Float16)fc1w[n * 128 + k];
    }
    for (int i = gtid; i < N * 64; i += gsz) {
        float2 f = ((const float2*)x)[i];
        ((__half2*)x16)[i] = __floats2half2_rn(f.x, f.y);
    }
    for (int e = gtid; e < E; e += gsz) atomicAdd(&bcnt[dst[e] >> 8], 1);
    __syncthreads();
    int c = bcnt[threadIdx.x];
    if (c > 0) atomicAdd(&bucket_cnt[threadIdx.x], c);
}

// ---------------- bucket prefix (1 block) ----------------
__global__ __launch_bounds__(256) void k_bscan(const int* __restrict__ bucket_cnt,
                                               int* __restrict__ bucket_base,
                                               int* __restrict__ bucket_cursor, int E) {
    __shared__ int s[256];
    int tx = threadIdx.x;
    int v = bucket_cnt[tx];
    s[tx] = v; __syncthreads();
    for (int off = 1; off < 256; off <<= 1) {
        int t = (tx >= off) ? s[tx - off] : 0;
        __syncthreads();
        s[tx] += t;
        __syncthreads();
    }
    int excl = s[tx] - v;
    bucket_base[tx] = excl;
    bucket_cursor[tx] = excl;
    if (tx == 0) bucket_base[256] = E;
}

// ---------------- binning fill: pairs (dlocal<<24 | src) grouped by bucket ----------------
__global__ __launch_bounds__(256) void k_bfill(const int* __restrict__ src, const int* __restrict__ dst,
                                               int* __restrict__ bucket_cursor,
                                               unsigned int* __restrict__ pairs, int E) {
    __shared__ int cnt[256];
    __shared__ int base[256];
    const int CH = 4096;
    int c0 = blockIdx.x * CH;
    int cend = c0 + CH < E ? c0 + CH : E;
    int tx = threadIdx.x;
    cnt[tx] = 0;
    __syncthreads();
    for (int i = c0 + tx; i < cend; i += 256) atomicAdd(&cnt[dst[i] >> 8], 1);
    __syncthreads();
    int myc = cnt[tx];
    int mybase = 0;
    if (myc > 0) mybase = atomicAdd(&bucket_cursor[tx], myc);
    __syncthreads();
    cnt[tx] = 0;
    base[tx] = mybase;
    __syncthreads();
    for (int i = c0 + tx; i < cend; i += 256) {
        int d = dst[i];
        int b = d >> 8;
        int pos = base[b] + atomicAdd(&cnt[b], 1);
        pairs[pos] = ((unsigned)(d & 255) << 24) | (unsigned)src[i];
    }
}

// -------- per-quarter-bucket: 16-padded CSR (self-in-list, pad=zero-row N) + desc + prescale
__global__ __launch_bounds__(256) void k_bsort(const unsigned int* __restrict__ pairs,
                                               const int* __restrict__ bucket_base,
                                               uint4* __restrict__ desc, float* __restrict__ dinv,
                                               int* __restrict__ csr, __half* __restrict__ x16,
                                               int N) {
    __shared__ int cnt[256], pre[256], cur[64];
    __shared__ float sdinv[256];
    __shared__ int stage[3584];
    const int B = blockIdx.x >> 2, q = blockIdx.x & 3;
    const int tx = threadIdx.x;
    const int pbase = bucket_base[B], pcnt = bucket_base[B + 1] - pbase;
    const int PB = pbase + B * 8192;   // padded bucket base
    cnt[tx] = 0;
    __syncthreads();
    for (int i = tx; i < pcnt; i += 256) atomicAdd(&cnt[pairs[pbase + i] >> 24], 1);
    __syncthreads();
    int deg = cnt[tx];
    int cnt16 = (deg + 16) & ~15;            // (deg + 1 self) rounded up to 16
    float dv = rsqrtf((float)deg + 1.0f);
    __syncthreads();
    cnt[tx] = cnt16;
    sdinv[tx] = dv;
    pre[tx] = cnt16;
    __syncthreads();
    for (int off = 1; off < 256; off <<= 1) {
        int t = (tx >= off) ? pre[tx - off] : 0;
        __syncthreads();
        pre[tx] += t;
        __syncthreads();
    }
    int excl = pre[tx] - cnt16;
    int node = B * 256 + tx;
    if (node < N) {
        desc[node] = make_uint4((unsigned)(PB + excl), (unsigned)(cnt16 >> 4),
                                __float_as_uint(dv), 0u);
        dinv[node] = dv;
    }
    __syncthreads();
    pre[tx] = excl;
    __syncthreads();
    const int d0 = q * 64;
    const int qstart = pre[d0];
    const int qcnt = pre[d0 + 63] + cnt[d0 + 63] - qstart;
    if (tx < 64) cur[tx] = pre[d0 + tx] - qstart + 1;   // slot 0 reserved for self
    __syncthreads();
    if (qcnt <= 3584) {
        for (int i = tx; i < qcnt; i += 256) stage[i] = N;   // zero-row pads
        __syncthreads();
        if (tx < 64) stage[pre[d0 + tx] - qstart] = B * 256 + d0 + tx;   // self first
        for (int i = tx; i < pcnt; i += 256) {
            unsigned p = pairs[pbase + i];
            int dl = (int)(p >> 24) - d0;
            if ((unsigned)dl < 64u) {
                int pos = atomicAdd(&cur[dl], 1);
                stage[pos] = (int)(p & 0xFFFFFFu);
            }
        }
        __syncthreads();
        for (int i = tx; i < qcnt; i += 256) csr[PB + qstart + i] = stage[i];
    } else {
        for (int i = tx; i < qcnt; i += 256) csr[PB + qstart + i] = N;
        __syncthreads();
        if (tx < 64) csr[PB + pre[d0 + tx]] = B * 256 + d0 + tx;
        for (int i = tx; i < pcnt; i += 256) {
            unsigned p = pairs[pbase + i];
            int dl = (int)(p >> 24) - d0;
            if ((unsigned)dl < 64u) {
                int pos = atomicAdd(&cur[dl], 1);
                csr[PB + qstart + pos] = (int)(p & 0xFFFFFFu);
            }
        }
    }
    // pre-scale x16 rows [B*256 + q*64, +64) by their dinv
    for (int i = tx; i < 64 * 64; i += 256) {
        int r = i >> 6, c = i & 63;
        int nd = B * 256 + q * 64 + r;
        if (nd < N) {
            float s = sdinv[q * 64 + r];
            float2 f = __half22float2(((__half2*)x16)[(size_t)nd * 64 + c]);
            ((__half2*)x16)[(size_t)nd * 64 + c] = __floats2half2_rn(f.x * s, f.y * s);
        }
    }
}

// ---------------- gather: desc-driven, branch-free 16-wide, self in list ----------------
template <bool BIASACT>
__global__ __launch_bounds__(256) void k_gather(const __half* __restrict__ X,
                                                const uint4* __restrict__ desc,
                                                const int* __restrict__ csr,
                                                const float* __restrict__ bias,
                                                __half* __restrict__ outp, int N) {
    int wid = __builtin_amdgcn_readfirstlane((int)((blockIdx.x * 256 + threadIdx.x) >> 6));
    if (wid >= N) return;
    int lane = threadIdx.x & 63, c = lane * 2;
    uint4 d = desc[wid];
    int k0 = __builtin_amdgcn_readfirstlane((int)d.x);
    int nit = __builtin_amdgcn_readfirstlane((int)d.y);
    float di = __uint_as_float(d.z);
    float accx = 0.f, accy = 0.f;
    for (int it = 0; it < nit; ++it) {
        int kk = k0 + it * 16;
        int ss[16];
        #pragma unroll
        for (int i = 0; i < 16; ++i) ss[i] = csr[kk + i];
        #pragma unroll
        for (int i = 0; i < 16; ++i) {
            float2 f = __half22float2(*(const __half2*)(X + (size_t)ss[i] * 128 + c));
            accx += f.x;
            accy += f.y;
        }
    }
    accx *= di;
    accy *= di;
    if (BIASACT) {
        accx = leaky(accx + bias[c]);
        accy = leaky(accy + bias[c + 1]);
    }
    *(__half2*)(outp + (size_t)wid * 128 + c) = __floats2half2_rn(accx, accy);
}

// ------- fused GEMM1+GEMM2 (64-row tile, 4 blocks/CU): t2' = (leaky(A@W1+b1)@W3)*dinv ------
__global__ __launch_bounds__(256, 4) void k_fused12(
    const __half* __restrict__ A1h, const _Float16* __restrict__ W1f,
    const _Float16* __restrict__ W3f, const float* __restrict__ b1,
    const float* __restrict__ dinv, __half* __restrict__ t2, int M)
{
    __shared__ __align__(16) _Float16 As[64 * 136];
    __shared__ __align__(16) _Float16 Hs[64 * 136];
    const int tid = threadIdx.x, lane = tid & 63, wid = tid >> 6;
    const int m0 = blockIdx.x * 64;
    // stage A tile [64][136]
    {
        const int r = tid >> 2, cq = tid & 3;
        int gr = m0 + r; if (gr >= M) gr = M - 1;
        const __half* Ar = A1h + (size_t)gr * 128;
        #pragma unroll
        for (int cc = 0; cc < 4; ++cc) {
            int ch = cq * 4 + cc;
            *(uint4*)(As + r * 136 + ch * 8) = *(const uint4*)(Ar + ch * 8);
        }
    }
    // bias preload
    float bq[4][2];
    #pragma unroll
    for (int q = 0; q < 4; ++q)
        #pragma unroll
        for (int n = 0; n < 2; ++n)
            bq[q][n] = b1[q * 128 + wid * 32 + n * 16 + (lane & 15)];
    __syncthreads();

    const int arow = lane & 15, kch = (lane >> 4) * 8;
    f32x4 acc2[4][2] = {};
    #pragma unroll
    for (int q = 0; q < 4; ++q) {
        f32x4 acc1[4][2] = {};
        #pragma unroll
        for (int ks = 0; ks < 4; ++ks) {
            f16x8 af[4], bf[2];
            #pragma unroll
            for (int i = 0; i < 4; ++i)
                af[i] = *(const f16x8*)(As + (i * 16 + arow) * 136 + ks * 32 + kch);
            #pragma unroll
            for (int n = 0; n < 2; ++n) {
                int cb = q * 8 + wid * 2 + n;
                bf[n] = *(const f16x8*)(W1f + ((size_t)(cb * 4 + ks) * 64 + lane) * 8);
            }
            #pragma unroll
            for (int i = 0; i < 4; ++i)
                #pragma unroll
                for (int n = 0; n < 2; ++n)
                    acc1[i][n] = __builtin_amdgcn_mfma_f32_16x16x32_f16(af[i], bf[n], acc1[i][n], 0, 0, 0);
        }
        __syncthreads();   // previous GEMM2 reads of Hs complete
        #pragma unroll
        for (int i = 0; i < 4; ++i)
            #pragma unroll
            for (int n = 0; n < 2; ++n)
                #pragma unroll
                for (int j = 0; j < 4; ++j) {
                    int row = i * 16 + (lane >> 4) * 4 + j;
                    int col = wid * 32 + n * 16 + (lane & 15);
                    Hs[row * 136 + col] = (_Float16)leaky(acc1[i][n][j] + bq[q][n]);
                }
        __syncthreads();
        #pragma unroll
        for (int ks = 0; ks < 4; ++ks) {
            f16x8 af[4], bf[2];
            #pragma unroll
            for (int i = 0; i < 4; ++i)
                af[i] = *(const f16x8*)(Hs + (i * 16 + arow) * 136 + ks * 32 + kch);
            #pragma unroll
            for (int n = 0; n < 2; ++n) {
                int cb = wid * 2 + n, ksg = q * 4 + ks;
                bf[n] = *(const f16x8*)(W3f + ((size_t)(cb * 16 + ksg) * 64 + lane) * 8);
            }
            #pragma unroll
            for (int i = 0; i < 4; ++i)
                #pragma unroll
                for (int n = 0; n < 2; ++n)
                    acc2[i][n] = __builtin_amdgcn_mfma_f32_16x16x32_f16(af[i], bf[n], acc2[i][n], 0, 0, 0);
        }
    }
    // epilogue: t2*dinv -> Hs, coalesced copy out
    __syncthreads();
    #pragma unroll
    for (int i = 0; i < 4; ++i)
        #pragma unroll
        for (int j = 0; j < 4; ++j) {
            int row = i * 16 + (lane >> 4) * 4 + j;
            int gr = m0 + row;
            float dv = dinv[gr < M ? gr : M - 1];
            #pragma unroll
            for (int n = 0; n < 2; ++n) {
                int col = wid * 32 + n * 16 + (lane & 15);
                Hs[row * 136 + col] = (_Float16)(acc2[i][n][j] * dv);
            }
        }
    __syncthreads();
    {
        const int r = tid >> 2, cq = tid & 3;
        int gr = m0 + r;
        if (gr < M) {
            #pragma unroll
            for (int cc = 0; cc < 4; ++cc) {
                int ch = cq * 4 + cc;
                *(uint4*)(t2 + (size_t)gr * 128 + ch * 8) = *(const uint4*)(Hs + r * 136 + ch * 8);
            }
        }
    }
}

// ---------------- GEMM3 + fc2 dot ----------------
__global__ __launch_bounds__(256, 2) void k_fgemm3(
    const __half* __restrict__ A3h, const _Float16* __restrict__ F1f,
    const float* __restrict__ fc1b, const float* __restrict__ fc2w,
    float* __restrict__ out, int M)
{
    __shared__ __align__(16) _Float16 As[128 * 136];
    const int tid = threadIdx.x, lane = tid & 63, wid = tid >> 6;
    const int wr = wid >> 1, wc = wid & 1;
    const int bx = blockIdx.x & 1, m0 = (blockIdx.x >> 1) * 128;
    const int nbase = bx * 128;
    {
        const int r = tid >> 1, hf = tid & 1;
        int gr = m0 + r; if (gr >= M) gr = M - 1;
        const __half* Ar = A3h + (size_t)gr * 128;
        #pragma unroll
        for (int c = 0; c < 8; ++c) {
            int ch = hf * 8 + c;
            *(uint4*)(As + r * 136 + ch * 8) = *(const uint4*)(Ar + ch * 8);
        }
    }
    __syncthreads();
    const int arow = lane & 15, kch = (lane >> 4) * 8;
    f32x4 acc[4][4] = {};
    #pragma unroll
    for (int ks = 0; ks < 4; ++ks) {
        f16x8 af[4], bf[4];
        #pragma unroll
        for (int i = 0; i < 4; ++i)
            af[i] = *(const f16x8*)(As + (wr * 64 + i * 16 + arow) * 136 + ks * 32 + kch);
        #pragma unroll
        for (int n = 0; n < 4; ++n) {
            int cb = bx * 8 + wc * 4 + n;
            bf[n] = *(const f16x8*)(F1f + ((size_t)(cb * 4 + ks) * 64 + lane) * 8);
        }
        #pragma unroll
        for (int i = 0; i < 4; ++i)
            #pragma unroll
            for (int n = 0; n < 4; ++n)
                acc[i][n] = __builtin_amdgcn_mfma_f32_16x16x32_f16(af[i], bf[n], acc[i][n], 0, 0, 0);
    }
    #pragma unroll
    for (int i = 0; i < 4; ++i)
        #pragma unroll
        for (int j = 0; j < 4; ++j) {
            int row = m0 + wr * 64 + i * 16 + (lane >> 4) * 4 + j;
            float s = 0.f;
            #pragma unroll
            for (int n = 0; n < 4; ++n) {
                int col = nbase + wc * 64 + n * 16 + (lane & 15);
                float v = leaky(acc[i][n][j] + fc1b[col]);
                s += v * fc2w[col];
            }
            s += __shfl_xor(s, 8);
            s += __shfl_xor(s, 4);
            s += __shfl_xor(s, 2);
            s += __shfl_xor(s, 1);
            if ((lane & 15) == 0 && row < M) atomicAdd(&out[row], s);
        }
}

extern "C" void kernel_launch(void* const* d_in, const int* in_sizes, int n_in,
                              void* d_out, int out_size, void* d_ws, size_t ws_size,
                              hipStream_t stream) {
    const float* x    = (const float*)d_in[0];
    const int*   ei   = (const int*)d_in[1];
    const float* W1   = (const float*)d_in[2];
    const float* b1   = (const float*)d_in[3];
    const float* W3   = (const float*)d_in[4];
    const float* b3   = (const float*)d_in[5];
    const float* fc1w = (const float*)d_in[6];
    const float* fc1b = (const float*)d_in[7];
    const float* fc2w = (const float*)d_in[8];
    const float* fc2b = (const float*)d_in[9];
    float* out = (float*)d_out;

    int N = in_sizes[0] / 128;   // 50000
    int E = in_sizes[1] / 2;     // 800000
    const int* src = ei;
    const int* dst = ei + E;

    const int NB = (N + 255) >> 8;      // 196
    char* ws = (char*)d_ws;
    size_t off = 0;
    auto alloc = [&](size_t bytes) { void* p = ws + off; off += (bytes + 255) & ~255ull; return p; };
    int*   bucket_cnt    = (int*)alloc(257 * 4);
    int*   bucket_base   = (int*)alloc(257 * 4);
    int*   bucket_cursor = (int*)alloc(257 * 4);
    uint4* desc   = (uint4*)alloc((size_t)N * 16);
    unsigned int* pairs = (unsigned int*)alloc((size_t)E * 4);
    int*   csr    = (int*)alloc(((size_t)E + (size_t)NB * 8192) * 4);
    float* dinv   = (float*)alloc((size_t)N * 4);
    __half* x16   = (__half*)alloc((size_t)(N + 1) * 128 * 2);
    __half* A1h   = (__half*)alloc((size_t)N * 128 * 2);
    __half* t2    = (__half*)alloc((size_t)(N + 1) * 128 * 2);
    __half* A3h   = (__half*)alloc((size_t)N * 128 * 2);
    _Float16* W1f = (_Float16*)alloc((size_t)32 * 4 * 64 * 8 * 2);
    _Float16* W3f = (_Float16*)alloc((size_t)8 * 16 * 64 * 8 * 2);
    _Float16* F1f = (_Float16*)alloc((size_t)16 * 4 * 64 * 8 * 2);
    (void)ws_size; (void)n_in; (void)out_size;

    const int MB128 = (N + 127) / 128;  // 391
    const int MB64  = (N + 63) / 64;    // 782
    dim3 blk(256);

    hipMemsetAsync(bucket_cnt, 0, 257 * 4, stream);

    // 1) prep
    k_prep_all<<<1024, blk, 0, stream>>>(x, W1, W3, fc1w, fc2b, dst, bucket_cnt,
                                         out, x16, t2, W1f, W3f, F1f, N, E);
    // 2) bucket prefix
    k_bscan<<<1, blk, 0, stream>>>(bucket_cnt, bucket_base, bucket_cursor, E);
    // 3) binning fill
    k_bfill<<<(E + 4095) / 4096, blk, 0, stream>>>(src, dst, bucket_cursor, pairs, E);
    // 4) 16-padded CSR + desc + dinv + x16 prescale
    k_bsort<<<NB * 4, blk, 0, stream>>>(pairs, bucket_base, desc, dinv, csr, x16, N);
    // 5) agg1' -> A1h
    k_gather<false><<<(N * 64 + 255) / 256, blk, 0, stream>>>(x16, desc, csr, nullptr, A1h, N);
    // 6) t2' = (leaky(A1h@W1+b1)@W3)*dinv
    k_fused12<<<MB64, blk, 0, stream>>>(A1h, W1f, W3f, b1, dinv, t2, N);
    // 7) h2 -> A3h
    k_gather<true><<<(N * 64 + 255) / 256, blk, 0, stream>>>(t2, desc, csr, b3, A3h, N);
    // 8) out
    k_fgemm3<<<MB128 * 2, blk, 0, stream>>>(A3h, F1f, fc1b, fc2w, out, N);
}